// Round 1
// 1363.680 us; speedup vs baseline: 1.7725x; 1.7725x over previous
//
#include <hip/hip_runtime.h>
#include <hip/hip_bf16.h>

#define NB 4
#define NT 16
#define ND 64
#define NHW 4096
#define NTOT (NB*NT*ND*NHW)   // 16,777,216 per plane

typedef __attribute__((ext_vector_type(8))) __bf16 bf16x8;
typedef __attribute__((ext_vector_type(4))) float f32x4;

// ---------------------------------------------------------------- spec reorder
__global__ void k_spec_reorder(const float* __restrict__ wr, const float* __restrict__ wi,
                               float* __restrict__ outr, float* __restrict__ outi) {
  int idx = blockIdx.x * 256 + threadIdx.x;      // D*HW = 262144
  int d = idx >> 12;
  int rc = idx & 4095;
  int r = rc >> 6, c = rc & 63;
  int br = __brev((unsigned)r) >> 26;
  int bc = __brev((unsigned)c) >> 26;
  int src = (d << 12) + (br << 6) + bc;
  outr[idx] = wr[src];
  outi[idx] = wi[src];
}

// ---------------------------------------------------------------- complex LN
__global__ void k_ln(const float* __restrict__ xr, const float* __restrict__ xi,
                     const float* __restrict__ g, const float* __restrict__ b,
                     float* __restrict__ outr, float* __restrict__ outi) {
  int pos = blockIdx.x * 256 + threadIdx.x;      // B*T*HW = 262144
  int bt = pos >> 12;
  int hw = pos & 4095;
  size_t base = (size_t)bt * ND * NHW + hw;
  float s = 0.f, ss = 0.f;
  for (int d = 0; d < ND; ++d) {
    float r = xr[base + (size_t)d * NHW];
    float im = xi[base + (size_t)d * NHW];
    s += r + im; ss += r * r + im * im;
  }
  float mean = s * (1.0f / 128.0f);
  float var = ss * (1.0f / 128.0f) - mean * mean;
  float rstd = rsqrtf(var + 1e-5f);
  for (int d = 0; d < ND; ++d) {
    float r = xr[base + (size_t)d * NHW];
    float im = xi[base + (size_t)d * NHW];
    outr[base + (size_t)d * NHW] = (r - mean) * rstd * g[d] + b[d];
    outi[base + (size_t)d * NHW] = (im - mean) * rstd * g[64 + d] + b[64 + d];
  }
}

// ---------------------------------------------------------------- conv weight repack
// wcp[(((tap*8 + nt)*4 + kt)*64 + lane)*8 + j] = W[oc = nt*16+(lane&15)][ic = kt*32+(lane>>4)*8+j][tap]
__global__ void k_wconv_repack(const float* __restrict__ w, __hip_bfloat16* __restrict__ wcp) {
  int idx = blockIdx.x * 256 + threadIdx.x;   // 147456 = 9*8*4*64*8
  int j = idx & 7;
  int lane = (idx >> 3) & 63;
  int kt = (idx >> 9) & 3;
  int nt = (idx >> 11) & 7;
  int tap = idx >> 14;
  int ic = kt * 32 + (lane >> 4) * 8 + j;
  int oc = nt * 16 + (lane & 15);
  wcp[idx] = __float2bfloat16(w[((size_t)(oc * 128 + ic)) * 9 + tap]);
}

// ---------------------------------------------------------------- 3x3 conv via MFMA (implicit GEMM)
// block: one (bt, row y). M = 64 positions, N = 128 oc, K = 9 taps * 128 ic.
// LDS: 3 rows x 66 cols x 128 ic bf16, [pos][ic] layout, XOR-swizzled (byte ^= (pos&7)<<4).
__global__ __launch_bounds__(256) void k_conv_mfma(
    const float* __restrict__ xsr, const float* __restrict__ xsi,
    const __hip_bfloat16* __restrict__ wcp, const float* __restrict__ bias,
    __hip_bfloat16* __restrict__ cr, __hip_bfloat16* __restrict__ ci) {
  __shared__ __align__(16) __bf16 lin[3 * 66 * 128];   // 50688 B
  int blk = blockIdx.x;            // bt*64 + y
  int y = blk & 63;
  int bt = blk >> 6;
  int tid = threadIdx.x;
  int lane = tid & 63, wave = tid >> 6;
  int lc = lane & 15, quad = lane >> 4;

  // ---- stage 3 input rows (halo cols, zero pad), fp32 -> bf16, swizzled b128 writes ----
  for (int i = tid; i < 48 * 66; i += 256) {
    int p = i / 66;                 // p = ky*16 + icg
    int pos = i - p * 66;
    int ky = p >> 4, icg = p & 15;
    int gy = y + ky - 1, gx = pos - 1;
    float vals[8];
#pragma unroll
    for (int k = 0; k < 8; ++k) vals[k] = 0.f;
    if (gy >= 0 && gy < 64 && gx >= 0 && gx < 64) {
      const float* src = (icg < 8) ? xsr : xsi;
      size_t pbase = ((size_t)(bt * 64 + (icg & 7) * 8)) * NHW + gy * 64 + gx;
#pragma unroll
      for (int k = 0; k < 8; ++k) vals[k] = src[pbase + (size_t)k * NHW];
    }
    bf16x8 v;
#pragma unroll
    for (int k = 0; k < 8; ++k) v[k] = (__bf16)vals[k];
    int elem = ((ky * 66 + pos) * 128 + icg * 8) ^ ((pos & 7) << 3);  // element-unit XOR == byte^((pos&7)<<4)
    *(bf16x8*)(lin + elem) = v;
  }
  __syncthreads();

  // ---- MFMA main loop: wave owns 32 pos (2 mt) x 64 oc (4 nt) ----
  int mt0 = (wave >> 1) * 2;       // 0 or 2
  int ocb = (wave & 1) * 4;        // n-tile base: 0 or 4
  f32x4 acc[2][4];
#pragma unroll
  for (int m = 0; m < 2; ++m)
#pragma unroll
    for (int n = 0; n < 4; ++n) acc[m][n] = (f32x4){0.f, 0.f, 0.f, 0.f};

  for (int ky = 0; ky < 3; ++ky) {
#pragma unroll
    for (int kt = 0; kt < 4; ++kt) {
      bf16x8 a[3][2];
#pragma unroll
      for (int kx = 0; kx < 3; ++kx)
#pragma unroll
        for (int m = 0; m < 2; ++m) {
          int pos = (mt0 + m) * 16 + lc + kx;
          int elem = ((ky * 66 + pos) * 128 + kt * 32 + quad * 8) ^ ((pos & 7) << 3);
          a[kx][m] = *(const bf16x8*)(lin + elem);
        }
#pragma unroll
      for (int kx = 0; kx < 3; ++kx) {
        const __hip_bfloat16* wp =
            wcp + ((((size_t)(ky * 3 + kx) * 8 + ocb) * 4 + kt) * 64 + lane) * 8;
#pragma unroll
        for (int n = 0; n < 4; ++n) {
          bf16x8 b = *(const bf16x8*)(const void*)(wp + (size_t)n * (4 * 64 * 8));
#pragma unroll
          for (int m = 0; m < 2; ++m)
            acc[m][n] = __builtin_amdgcn_mfma_f32_16x16x32_bf16(a[kx][m], b, acc[m][n], 0, 0, 0);
        }
      }
    }
  }
  __syncthreads();   // all LDS reads done; reuse lin as output staging [128][66] bf16

  __bf16* lout = lin;
#pragma unroll
  for (int n = 0; n < 4; ++n) {
    int oc = (ocb + n) * 16 + lc;
    float bb = bias[oc];
#pragma unroll
    for (int m = 0; m < 2; ++m)
#pragma unroll
      for (int r = 0; r < 4; ++r)
        lout[oc * 66 + (mt0 + m) * 16 + quad * 4 + r] = (__bf16)(acc[m][n][r] + bb);
  }
  __syncthreads();

  // ---- coalesced global write: each lane writes 4B (2 cols) of one oc plane ----
  {
    int colh = (lane & 31) * 2;
    int ocl = lane >> 5;
#pragma unroll
    for (int it = 0; it < 16; ++it) {
      int oc = it * 8 + wave * 2 + ocl;
      __hip_bfloat16* dst = (oc < 64) ? cr : ci;
      size_t ob = ((size_t)(bt * 64 + (oc & 63))) * NHW + y * 64 + colh;
      *(unsigned int*)((void*)(dst + ob)) =
          *(const unsigned int*)((const void*)(lout + oc * 66 + colh));
    }
  }
}

// ---------------------------------------------------------------- FFT64 via shfl
__device__ __forceinline__ void fft64_fwd(float& re, float& im, int lane) {
#pragma unroll
  for (int m = 32; m >= 1; m >>= 1) {
    float pr = __shfl_xor(re, m, 64);
    float pi = __shfl_xor(im, m, 64);
    int j = lane & (m - 1);
    float ang = -3.14159265358979f * (float)j / (float)m;
    float s, c;
    __sincosf(ang, &s, &c);
    if (lane & m) {
      float tr = pr - re, ti = pi - im;
      re = tr * c - ti * s;
      im = tr * s + ti * c;
    } else { re += pr; im += pi; }
  }
}
__device__ __forceinline__ void fft64_inv(float& re, float& im, int lane) {
#pragma unroll
  for (int m = 1; m <= 32; m <<= 1) {
    int j = lane & (m - 1);
    float ang = 3.14159265358979f * (float)j / (float)m;
    float s, c;
    __sincosf(ang, &s, &c);
    float pr = __shfl_xor(re, m, 64);
    float pi = __shfl_xor(im, m, 64);
    if (lane & m) {
      float wr = re * c - im * s, wi = re * s + im * c;
      re = pr - wr; im = pi - wi;
    } else {
      float wr = pr * c - pi * s, wi = pr * s + pi * c;
      re += wr; im += wi;
    }
  }
}

__global__ __launch_bounds__(256) void k_fft_combine(
    float* xsr, float* xsi,
    const __hip_bfloat16* __restrict__ cr, const __hip_bfloat16* __restrict__ ci,
    const float* __restrict__ sbr, const float* __restrict__ sbi,
    const float* __restrict__ x0r, const float* __restrict__ x0i,
    const float* __restrict__ gate) {
  __shared__ float lr[64 * 65], li[64 * 65];
  int slice = blockIdx.x;                      // bt*64 + d
  int d = slice & 63;
  size_t base = (size_t)slice * NHW;
  int lane = threadIdx.x & 63, wv = threadIdx.x >> 6;
  float g = gate[0];
  for (int r = wv; r < 64; r += 4) {
    float re = xsr[base + r * 64 + lane];
    float im = xsi[base + r * 64 + lane];
    fft64_fwd(re, im, lane);
    lr[r * 65 + lane] = re; li[r * 65 + lane] = im;
  }
  __syncthreads();
  for (int c = wv; c < 64; c += 4) {
    float re = lr[lane * 65 + c], im = li[lane * 65 + c];
    fft64_fwd(re, im, lane);
    lr[lane * 65 + c] = re; li[lane * 65 + c] = im;
  }
  __syncthreads();
  for (int r = wv; r < 64; r += 4) {
    float re = lr[r * 65 + lane], im = li[r * 65 + lane];
    float sr = sbr[(size_t)d * NHW + r * 64 + lane];
    float si = sbi[(size_t)d * NHW + r * 64 + lane];
    float nr = re * sr - im * si, ni = re * si + im * sr;
    fft64_inv(nr, ni, lane);
    lr[r * 65 + lane] = nr * (1.0f / 64.0f);
    li[r * 65 + lane] = ni * (1.0f / 64.0f);
  }
  __syncthreads();
  for (int c = wv; c < 64; c += 4) {
    float re = lr[lane * 65 + c], im = li[lane * 65 + c];
    fft64_inv(re, im, lane);
    lr[lane * 65 + c] = re * (1.0f / 64.0f);
    li[lane * 65 + c] = im * (1.0f / 64.0f);
  }
  __syncthreads();
  for (int r = wv; r < 64; r += 4) {
    size_t off = base + r * 64 + lane;
    float spr = lr[r * 65 + lane], spi = li[r * 65 + lane];
    float outr = g * __bfloat162float(cr[off]) + (1.f - g) * spr + x0r[off];
    float outi = g * __bfloat162float(ci[off]) + (1.f - g) * spi + x0i[off];
    xsr[off] = outr; xsi[off] = outi;
  }
}

// ---------------------------------------------------------------- temporal (fused)
__global__ __launch_bounds__(256) void k_temporal(
    float* xsr, const float* xsi,
    const float* __restrict__ lng, const float* __restrict__ lnb,
    const float* __restrict__ lam_r, const float* __restrict__ lam_i,
    const float* __restrict__ dtv,
    const float* __restrict__ er, const float* __restrict__ ei,
    const float* __restrict__ dmr, const float* __restrict__ dmi) {
  __shared__ float ur[64][32], ui[64][32];
  __shared__ float hr[64][32], hi[64][32];
  __shared__ float red_s[8][32], red_ss[8][32];
  __shared__ float decr[64], deci[64], forr[64], fori[64];
  int b = blockIdx.x >> 7;
  int hw0 = (blockIdx.x & 127) << 5;
  int tid = threadIdx.x;
  int hwL = tid & 31, q = tid >> 5;
  if (tid < 64) {
    float lrv = lam_r[tid], liv = lam_i[tid];
    float dtb = dtv[b];
    float mg = __expf(lrv * dtb);
    float s, c;
    __sincosf(liv * dtb, &s, &c);
    float der = mg * c, dei = mg * s;
    float nr = der - 1.0f, ni = dei;
    float dn = 1.0f / (lrv * lrv + liv * liv);
    decr[tid] = der; deci[tid] = dei;
    forr[tid] = (nr * lrv + ni * liv) * dn;
    fori[tid] = (ni * lrv - nr * liv) * dn;
  }
  for (int i = tid; i < 64 * 32; i += 256) { (&hr[0][0])[i] = 0.f; (&hi[0][0])[i] = 0.f; }
  __syncthreads();
  for (int t = 0; t < NT; ++t) {
    size_t base = ((size_t)((b * NT + t) * ND)) * NHW + hw0;
#pragma unroll
    for (int k = 0; k < 8; ++k) {
      int dd = q * 8 + k;
      ur[dd][hwL] = xsr[base + (size_t)dd * NHW + hwL];
      ui[dd][hwL] = xsi[base + (size_t)dd * NHW + hwL];
    }
    __syncthreads();
    {
      float s0 = 0.f, s1 = 0.f;
#pragma unroll
      for (int k = 0; k < 16; ++k) {
        int v = q * 16 + k;
        float x = (q < 4) ? ur[v][hwL] : ui[v - 64][hwL];
        s0 += x; s1 += x * x;
      }
      red_s[q][hwL] = s0; red_ss[q][hwL] = s1;
    }
    __syncthreads();
    float s = 0.f, ss = 0.f;
#pragma unroll
    for (int k = 0; k < 8; ++k) { s += red_s[k][hwL]; ss += red_ss[k][hwL]; }
    float mean = s * 0.0078125f;
    float rstd = rsqrtf(ss * 0.0078125f - mean * mean + 1e-5f);
#pragma unroll
    for (int k = 0; k < 16; ++k) {
      int v = q * 16 + k;
      if (q < 4) ur[v][hwL] = (ur[v][hwL] - mean) * rstd * lng[v] + lnb[v];
      else       ui[v - 64][hwL] = (ui[v - 64][hwL] - mean) * rstd * lng[v] + lnb[v];
    }
    __syncthreads();
    float ar[8], ac[8];
#pragma unroll
    for (int j = 0; j < 8; ++j) { ar[j] = 0.f; ac[j] = 0.f; }
    for (int d2 = 0; d2 < 64; ++d2) {
      float xr = ur[d2][hwL], xi2 = ui[d2][hwL];
      float wre[8], wim[8];
      *(float4*)&wre[0] = *(const float4*)(er + d2 * 64 + q * 8);
      *(float4*)&wre[4] = *(const float4*)(er + d2 * 64 + q * 8 + 4);
      *(float4*)&wim[0] = *(const float4*)(ei + d2 * 64 + q * 8);
      *(float4*)&wim[4] = *(const float4*)(ei + d2 * 64 + q * 8 + 4);
#pragma unroll
      for (int j = 0; j < 8; ++j) {
        ar[j] += xr * wre[j] - xi2 * wim[j];
        ac[j] += xr * wim[j] + xi2 * wre[j];
      }
    }
#pragma unroll
    for (int j = 0; j < 8; ++j) {
      int ed = q * 8 + j;
      float h0r = hr[ed][hwL], h0i = hi[ed][hwL];
      float nr2 = h0r * decr[ed] - h0i * deci[ed] + ar[j] * forr[ed] - ac[j] * fori[ed];
      float ni2 = h0r * deci[ed] + h0i * decr[ed] + ar[j] * fori[ed] + ac[j] * forr[ed];
      hr[ed][hwL] = nr2; hi[ed][hwL] = ni2;
    }
    __syncthreads();
    float da[8];
#pragma unroll
    for (int j = 0; j < 8; ++j) da[j] = 0.f;
    for (int ed = 0; ed < 64; ++ed) {
      float h2r = hr[ed][hwL], h2i = hi[ed][hwL];
      float wre[8], wim[8];
      *(float4*)&wre[0] = *(const float4*)(dmr + ed * 64 + q * 8);
      *(float4*)&wre[4] = *(const float4*)(dmr + ed * 64 + q * 8 + 4);
      *(float4*)&wim[0] = *(const float4*)(dmi + ed * 64 + q * 8);
      *(float4*)&wim[4] = *(const float4*)(dmi + ed * 64 + q * 8 + 4);
#pragma unroll
      for (int j = 0; j < 8; ++j) da[j] += h2r * wre[j] - h2i * wim[j];
    }
#pragma unroll
    for (int j = 0; j < 8; ++j) {
      int dd = q * 8 + j;
      xsr[base + (size_t)dd * NHW + hwL] += da[j];
    }
    __syncthreads();
  }
}

// ---------------------------------------------------------------- weight repack (bf16, MFMA B-fragment order)
__global__ void k_repack(const float* __restrict__ w1, const float* __restrict__ w2,
                         __hip_bfloat16* __restrict__ w1p, __hip_bfloat16* __restrict__ w2p) {
  int idx = blockIdx.x * 256 + threadIdx.x;   // 131072
  if (idx < 65536) {
    int j = idx & 7, lane = (idx >> 3) & 63, kt = (idx >> 9) & 3, nt = idx >> 11;
    int k = kt * 32 + (lane >> 4) * 8 + j;
    int n = nt * 16 + (lane & 15);
    w1p[idx] = __float2bfloat16(w1[k * 512 + n]);
  } else {
    int i2 = idx - 65536;
    int j = i2 & 7, lane = (i2 >> 3) & 63, kt = (i2 >> 9) & 15, nt = i2 >> 13;
    int k = kt * 32 + (lane >> 4) * 8 + j;
    int n = nt * 16 + (lane & 15);
    w2p[i2] = __float2bfloat16(w2[k * 128 + n]);
  }
}

// ---------------------------------------------------------------- channel MLP via MFMA
__global__ __launch_bounds__(256, 3) void k_mlp_mfma(
    const float* __restrict__ xsr, const float* __restrict__ xsi,
    const __hip_bfloat16* __restrict__ w1p, const __hip_bfloat16* __restrict__ w2p,
    const float* __restrict__ b1, const float* __restrict__ b2,
    float* __restrict__ out) {
  __shared__ __bf16 lf[32 * 136];          // f bf16, row stride 136
  __shared__ __bf16 lh[32 * 520];          // h1 bf16, row stride 520 (reused as fp32 out[128][33])
  float* lo = (float*)lh;
  int blk = blockIdx.x;                    // 8192 = bt*128 + hwtile
  int bt = blk >> 7;
  int hw0 = (blk & 127) << 5;
  int tid = threadIdx.x;
  int lane = tid & 63, wave = tid >> 6;
  int lc = lane & 15, quad = lane >> 4;
  // ---- stage f (fp32 global -> bf16 LDS) ----
  {
    int tok = tid & 31, cg = tid >> 5;
#pragma unroll
    for (int it = 0; it < 16; ++it) {
      int c = it * 8 + cg;
      const float* src = (c < 64) ? (xsr + ((size_t)(bt * 64 + c)) * NHW)
                                  : (xsi + ((size_t)(bt * 64 + c - 64)) * NHW);
      lf[tok * 136 + c] = (__bf16)src[hw0 + tok];
    }
  }
  __syncthreads();
  // ---- GEMM1: h1[32][512], wave owns cols wave*128..+127 ----
  f32x4 acc[2][8];
#pragma unroll
  for (int mt = 0; mt < 2; ++mt)
#pragma unroll
    for (int nt = 0; nt < 8; ++nt) acc[mt][nt] = (f32x4){0.f, 0.f, 0.f, 0.f};
#pragma unroll
  for (int kt = 0; kt < 4; ++kt) {
    bf16x8 a0 = *(const bf16x8*)&lf[lc * 136 + kt * 32 + quad * 8];
    bf16x8 a1 = *(const bf16x8*)&lf[(lc + 16) * 136 + kt * 32 + quad * 8];
    const __hip_bfloat16* wp = w1p + (((size_t)(wave * 8) * 4 + kt) * 64 + lane) * 8;
#pragma unroll
    for (int nt = 0; nt < 8; ++nt) {
      bf16x8 b = *(const bf16x8*)(const void*)(wp + (size_t)nt * (4 * 64 * 8));
      acc[0][nt] = __builtin_amdgcn_mfma_f32_16x16x32_bf16(a0, b, acc[0][nt], 0, 0, 0);
      acc[1][nt] = __builtin_amdgcn_mfma_f32_16x16x32_bf16(a1, b, acc[1][nt], 0, 0, 0);
    }
  }
  // ---- gelu -> lh (bf16) ----
#pragma unroll
  for (int nt = 0; nt < 8; ++nt) {
    int col = wave * 128 + nt * 16 + lc;
    float bb = b1[col];
#pragma unroll
    for (int mt = 0; mt < 2; ++mt)
#pragma unroll
      for (int r = 0; r < 4; ++r) {
        float x = acc[mt][nt][r] + bb;
        float y = 0.7978845608f * (x + 0.044715f * x * x * x);
        float e = __expf(2.0f * y);
        float th = 1.0f - 2.0f / (e + 1.0f);
        float gv = 0.5f * x * (1.0f + th);
        lh[(mt * 16 + quad * 4 + r) * 520 + col] = (__bf16)gv;
      }
  }
  __syncthreads();
  // ---- GEMM2: out[32][128], wave owns cols wave*32..+31 ----
  f32x4 acc2[2][2];
#pragma unroll
  for (int mt = 0; mt < 2; ++mt)
#pragma unroll
    for (int n = 0; n < 2; ++n) acc2[mt][n] = (f32x4){0.f, 0.f, 0.f, 0.f};
#pragma unroll
  for (int kt = 0; kt < 16; ++kt) {
    bf16x8 a0 = *(const bf16x8*)&lh[lc * 520 + kt * 32 + quad * 8];
    bf16x8 a1 = *(const bf16x8*)&lh[(lc + 16) * 520 + kt * 32 + quad * 8];
#pragma unroll
    for (int n = 0; n < 2; ++n) {
      bf16x8 b = *(const bf16x8*)(const void*)(w2p + (((size_t)(wave * 2 + n) * 16 + kt) * 64 + lane) * 8);
      acc2[0][n] = __builtin_amdgcn_mfma_f32_16x16x32_bf16(a0, b, acc2[0][n], 0, 0, 0);
      acc2[1][n] = __builtin_amdgcn_mfma_f32_16x16x32_bf16(a1, b, acc2[1][n], 0, 0, 0);
    }
  }
  __syncthreads();   // all lh reads done; reuse as fp32 out staging
  // ---- epilogue: acc2 + b2 -> lo[c][tok] ----
#pragma unroll
  for (int n = 0; n < 2; ++n) {
    int c = wave * 32 + n * 16 + lc;
    float bb = b2[c];
#pragma unroll
    for (int mt = 0; mt < 2; ++mt)
#pragma unroll
      for (int r = 0; r < 4; ++r)
        lo[c * 33 + mt * 16 + quad * 4 + r] = acc2[mt][n][r] + bb;
  }
  __syncthreads();
  // ---- final: out = lo + f_resid (fp32), coalesced ----
  {
    int tok = tid & 31, cg = tid >> 5;
#pragma unroll
    for (int it = 0; it < 16; ++it) {
      int c = it * 8 + cg;
      const float* src = (c < 64) ? (xsr + ((size_t)(bt * 64 + c)) * NHW)
                                  : (xsi + ((size_t)(bt * 64 + c - 64)) * NHW);
      out[((size_t)(bt * 128 + c)) * NHW + hw0 + tok] = lo[c * 33 + tok] + src[hw0 + tok];
    }
  }
}

// ---------------------------------------------------------------- launch
extern "C" void kernel_launch(void* const* d_in, const int* in_sizes, int n_in,
                              void* d_out, int out_size, void* d_ws, size_t ws_size,
                              hipStream_t stream) {
  const float* x_r    = (const float*)d_in[0];
  const float* x_i    = (const float*)d_in[1];
  const float* dt     = (const float*)d_in[2];
  const float* ln_s_g = (const float*)d_in[3];
  const float* ln_s_b = (const float*)d_in[4];
  const float* conv_w = (const float*)d_in[5];
  const float* conv_b = (const float*)d_in[6];
  const float* spec_wr= (const float*)d_in[7];
  const float* spec_wi= (const float*)d_in[8];
  const float* gate   = (const float*)d_in[9];
  const float* ln_t_g = (const float*)d_in[10];
  const float* ln_t_b = (const float*)d_in[11];
  const float* lam_r  = (const float*)d_in[12];
  const float* lam_i  = (const float*)d_in[13];
  const float* enc_r  = (const float*)d_in[14];
  const float* enc_i  = (const float*)d_in[15];
  const float* dec_r  = (const float*)d_in[16];
  const float* dec_i  = (const float*)d_in[17];
  const float* p_w1   = (const float*)d_in[18];
  const float* p_b1   = (const float*)d_in[19];
  const float* p_w2   = (const float*)d_in[20];
  const float* p_b2   = (const float*)d_in[21];

  float* ws   = (float*)d_ws;
  float* xs_r = ws;                       // N fp32
  float* xs_i = ws + (size_t)NTOT;        // N fp32
  float* sbr  = ws + (size_t)2 * NTOT;    // D*HW fp32
  float* sbi  = sbr + (size_t)ND * NHW;
  __hip_bfloat16* cl_r = (__hip_bfloat16*)(sbi + (size_t)ND * NHW);  // N bf16
  __hip_bfloat16* cl_i = cl_r + (size_t)NTOT;                        // N bf16
  // repacked MLP weights overlap cl_r region (conv outputs dead after k_fft_combine)
  __hip_bfloat16* w1p = cl_r;             // 65536 bf16
  __hip_bfloat16* w2p = w1p + 65536;      // 65536 bf16
  // packed conv weights live in d_out (dead until k_mlp_mfma writes it)
  __hip_bfloat16* wcp = (__hip_bfloat16*)d_out;   // 147456 bf16

  k_spec_reorder<<<1024, 256, 0, stream>>>(spec_wr, spec_wi, sbr, sbi);
  k_wconv_repack<<<576, 256, 0, stream>>>(conv_w, wcp);
  k_ln<<<1024, 256, 0, stream>>>(x_r, x_i, ln_s_g, ln_s_b, xs_r, xs_i);
  k_conv_mfma<<<4096, 256, 0, stream>>>(xs_r, xs_i, wcp, conv_b, cl_r, cl_i);
  k_fft_combine<<<4096, 256, 0, stream>>>(xs_r, xs_i, cl_r, cl_i, sbr, sbi, x_r, x_i, gate);
  k_repack<<<512, 256, 0, stream>>>(p_w1, p_w2, w1p, w2p);
  k_temporal<<<512, 256, 0, stream>>>(xs_r, xs_i, ln_t_g, ln_t_b, lam_r, lam_i, dt,
                                      enc_r, enc_i, dec_r, dec_i);
  k_mlp_mfma<<<8192, 256, 0, stream>>>(xs_r, xs_i, w1p, w2p, p_b1, p_b2, (float*)d_out);
}

// Round 2
// 940.841 us; speedup vs baseline: 2.5691x; 1.4494x over previous
//
#include <hip/hip_runtime.h>
#include <hip/hip_bf16.h>

#define NB 4
#define NT 16
#define ND 64
#define NHW 4096
#define NTOT (NB*NT*ND*NHW)   // 16,777,216 per plane

typedef __attribute__((ext_vector_type(8))) __bf16 bf16x8;
typedef __attribute__((ext_vector_type(4))) float f32x4;

// ---------------------------------------------------------------- spec reorder
__global__ void k_spec_reorder(const float* __restrict__ wr, const float* __restrict__ wi,
                               float* __restrict__ outr, float* __restrict__ outi) {
  int idx = blockIdx.x * 256 + threadIdx.x;      // D*HW = 262144
  int d = idx >> 12;
  int rc = idx & 4095;
  int r = rc >> 6, c = rc & 63;
  int br = __brev((unsigned)r) >> 26;
  int bc = __brev((unsigned)c) >> 26;
  int src = (d << 12) + (br << 6) + bc;
  outr[idx] = wr[src];
  outi[idx] = wi[src];
}

// ---------------------------------------------------------------- complex LN (spatial)
__global__ void k_ln(const float* __restrict__ xr, const float* __restrict__ xi,
                     const float* __restrict__ g, const float* __restrict__ b,
                     float* __restrict__ outr, float* __restrict__ outi) {
  int pos = blockIdx.x * 256 + threadIdx.x;      // B*T*HW = 262144
  int bt = pos >> 12;
  int hw = pos & 4095;
  size_t base = (size_t)bt * ND * NHW + hw;
  float s = 0.f, ss = 0.f;
  for (int d = 0; d < ND; ++d) {
    float r = xr[base + (size_t)d * NHW];
    float im = xi[base + (size_t)d * NHW];
    s += r + im; ss += r * r + im * im;
  }
  float mean = s * (1.0f / 128.0f);
  float var = ss * (1.0f / 128.0f) - mean * mean;
  float rstd = rsqrtf(var + 1e-5f);
  for (int d = 0; d < ND; ++d) {
    float r = xr[base + (size_t)d * NHW];
    float im = xi[base + (size_t)d * NHW];
    outr[base + (size_t)d * NHW] = (r - mean) * rstd * g[d] + b[d];
    outi[base + (size_t)d * NHW] = (im - mean) * rstd * g[64 + d] + b[64 + d];
  }
}

// ---------------------------------------------------------------- conv weight repack
__global__ void k_wconv_repack(const float* __restrict__ w, __hip_bfloat16* __restrict__ wcp) {
  int idx = blockIdx.x * 256 + threadIdx.x;   // 147456 = 9*8*4*64*8
  int j = idx & 7;
  int lane = (idx >> 3) & 63;
  int kt = (idx >> 9) & 3;
  int nt = (idx >> 11) & 7;
  int tap = idx >> 14;
  int ic = kt * 32 + (lane >> 4) * 8 + j;
  int oc = nt * 16 + (lane & 15);
  wcp[idx] = __float2bfloat16(w[((size_t)(oc * 128 + ic)) * 9 + tap]);
}

// ---------------------------------------------------------------- 3x3 conv via MFMA (implicit GEMM)
__global__ __launch_bounds__(256) void k_conv_mfma(
    const float* __restrict__ xsr, const float* __restrict__ xsi,
    const __hip_bfloat16* __restrict__ wcp, const float* __restrict__ bias,
    __hip_bfloat16* __restrict__ cr, __hip_bfloat16* __restrict__ ci) {
  __shared__ __align__(16) __bf16 lin[3 * 66 * 128];   // 50688 B
  int blk = blockIdx.x;            // bt*64 + y
  int y = blk & 63;
  int bt = blk >> 6;
  int tid = threadIdx.x;
  int lane = tid & 63, wave = tid >> 6;
  int lc = lane & 15, quad = lane >> 4;

  for (int i = tid; i < 48 * 66; i += 256) {
    int p = i / 66;                 // p = ky*16 + icg
    int pos = i - p * 66;
    int ky = p >> 4, icg = p & 15;
    int gy = y + ky - 1, gx = pos - 1;
    float vals[8];
#pragma unroll
    for (int k = 0; k < 8; ++k) vals[k] = 0.f;
    if (gy >= 0 && gy < 64 && gx >= 0 && gx < 64) {
      const float* src = (icg < 8) ? xsr : xsi;
      size_t pbase = ((size_t)(bt * 64 + (icg & 7) * 8)) * NHW + gy * 64 + gx;
#pragma unroll
      for (int k = 0; k < 8; ++k) vals[k] = src[pbase + (size_t)k * NHW];
    }
    bf16x8 v;
#pragma unroll
    for (int k = 0; k < 8; ++k) v[k] = (__bf16)vals[k];
    int elem = ((ky * 66 + pos) * 128 + icg * 8) ^ ((pos & 7) << 3);
    *(bf16x8*)(lin + elem) = v;
  }
  __syncthreads();

  int mt0 = (wave >> 1) * 2;       // 0 or 2
  int ocb = (wave & 1) * 4;        // n-tile base: 0 or 4
  f32x4 acc[2][4];
#pragma unroll
  for (int m = 0; m < 2; ++m)
#pragma unroll
    for (int n = 0; n < 4; ++n) acc[m][n] = (f32x4){0.f, 0.f, 0.f, 0.f};

  for (int ky = 0; ky < 3; ++ky) {
#pragma unroll
    for (int kt = 0; kt < 4; ++kt) {
      bf16x8 a[3][2];
#pragma unroll
      for (int kx = 0; kx < 3; ++kx)
#pragma unroll
        for (int m = 0; m < 2; ++m) {
          int pos = (mt0 + m) * 16 + lc + kx;
          int elem = ((ky * 66 + pos) * 128 + kt * 32 + quad * 8) ^ ((pos & 7) << 3);
          a[kx][m] = *(const bf16x8*)(lin + elem);
        }
#pragma unroll
      for (int kx = 0; kx < 3; ++kx) {
        const __hip_bfloat16* wp =
            wcp + ((((size_t)(ky * 3 + kx) * 8 + ocb) * 4 + kt) * 64 + lane) * 8;
#pragma unroll
        for (int n = 0; n < 4; ++n) {
          bf16x8 b = *(const bf16x8*)(const void*)(wp + (size_t)n * (4 * 64 * 8));
#pragma unroll
          for (int m = 0; m < 2; ++m)
            acc[m][n] = __builtin_amdgcn_mfma_f32_16x16x32_bf16(a[kx][m], b, acc[m][n], 0, 0, 0);
        }
      }
    }
  }
  __syncthreads();

  __bf16* lout = lin;
#pragma unroll
  for (int n = 0; n < 4; ++n) {
    int oc = (ocb + n) * 16 + lc;
    float bb = bias[oc];
#pragma unroll
    for (int m = 0; m < 2; ++m)
#pragma unroll
      for (int r = 0; r < 4; ++r)
        lout[oc * 66 + (mt0 + m) * 16 + quad * 4 + r] = (__bf16)(acc[m][n][r] + bb);
  }
  __syncthreads();

  {
    int colh = (lane & 31) * 2;
    int ocl = lane >> 5;
#pragma unroll
    for (int it = 0; it < 16; ++it) {
      int oc = it * 8 + wave * 2 + ocl;
      __hip_bfloat16* dst = (oc < 64) ? cr : ci;
      size_t ob = ((size_t)(bt * 64 + (oc & 63))) * NHW + y * 64 + colh;
      *(unsigned int*)((void*)(dst + ob)) =
          *(const unsigned int*)((const void*)(lout + oc * 66 + colh));
    }
  }
}

// ---------------------------------------------------------------- FFT64 via shfl
__device__ __forceinline__ void fft64_fwd(float& re, float& im, int lane) {
#pragma unroll
  for (int m = 32; m >= 1; m >>= 1) {
    float pr = __shfl_xor(re, m, 64);
    float pi = __shfl_xor(im, m, 64);
    int j = lane & (m - 1);
    float ang = -3.14159265358979f * (float)j / (float)m;
    float s, c;
    __sincosf(ang, &s, &c);
    if (lane & m) {
      float tr = pr - re, ti = pi - im;
      re = tr * c - ti * s;
      im = tr * s + ti * c;
    } else { re += pr; im += pi; }
  }
}
__device__ __forceinline__ void fft64_inv(float& re, float& im, int lane) {
#pragma unroll
  for (int m = 1; m <= 32; m <<= 1) {
    int j = lane & (m - 1);
    float ang = 3.14159265358979f * (float)j / (float)m;
    float s, c;
    __sincosf(ang, &s, &c);
    float pr = __shfl_xor(re, m, 64);
    float pi = __shfl_xor(im, m, 64);
    if (lane & m) {
      float wr = re * c - im * s, wi = re * s + im * c;
      re = pr - wr; im = pi - wi;
    } else {
      float wr = pr * c - pi * s, wi = pr * s + pi * c;
      re += wr; im += wi;
    }
  }
}

__global__ __launch_bounds__(256) void k_fft_combine(
    float* xsr, float* xsi,
    const __hip_bfloat16* __restrict__ cr, const __hip_bfloat16* __restrict__ ci,
    const float* __restrict__ sbr, const float* __restrict__ sbi,
    const float* __restrict__ x0r, const float* __restrict__ x0i,
    const float* __restrict__ gate) {
  __shared__ float lr[64 * 65], li[64 * 65];
  int slice = blockIdx.x;                      // bt*64 + d
  int d = slice & 63;
  size_t base = (size_t)slice * NHW;
  int lane = threadIdx.x & 63, wv = threadIdx.x >> 6;
  float g = gate[0];
  for (int r = wv; r < 64; r += 4) {
    float re = xsr[base + r * 64 + lane];
    float im = xsi[base + r * 64 + lane];
    fft64_fwd(re, im, lane);
    lr[r * 65 + lane] = re; li[r * 65 + lane] = im;
  }
  __syncthreads();
  for (int c = wv; c < 64; c += 4) {
    float re = lr[lane * 65 + c], im = li[lane * 65 + c];
    fft64_fwd(re, im, lane);
    lr[lane * 65 + c] = re; li[lane * 65 + c] = im;
  }
  __syncthreads();
  for (int r = wv; r < 64; r += 4) {
    float re = lr[r * 65 + lane], im = li[r * 65 + lane];
    float sr = sbr[(size_t)d * NHW + r * 64 + lane];
    float si = sbi[(size_t)d * NHW + r * 64 + lane];
    float nr = re * sr - im * si, ni = re * si + im * sr;
    fft64_inv(nr, ni, lane);
    lr[r * 65 + lane] = nr * (1.0f / 64.0f);
    li[r * 65 + lane] = ni * (1.0f / 64.0f);
  }
  __syncthreads();
  for (int c = wv; c < 64; c += 4) {
    float re = lr[lane * 65 + c], im = li[lane * 65 + c];
    fft64_inv(re, im, lane);
    lr[lane * 65 + c] = re * (1.0f / 64.0f);
    li[lane * 65 + c] = im * (1.0f / 64.0f);
  }
  __syncthreads();
  for (int r = wv; r < 64; r += 4) {
    size_t off = base + r * 64 + lane;
    float spr = lr[r * 65 + lane], spi = li[r * 65 + lane];
    float outr = g * __bfloat162float(cr[off]) + (1.f - g) * spr + x0r[off];
    float outi = g * __bfloat162float(ci[off]) + (1.f - g) * spi + x0i[off];
    xsr[off] = outr; xsi[off] = outi;
  }
}

// ---------------------------------------------------------------- all weight repacks (bf16, MFMA B-fragment order)
// w1p: 128x512, w2p: 512x128, encp: 128x128 [[Er,Ei],[-Ei,Er]], decp: 128x64 [Dmr;-Dmi]
__global__ void k_repack_all(const float* __restrict__ w1, const float* __restrict__ w2,
                             const float* __restrict__ er, const float* __restrict__ ei,
                             const float* __restrict__ dmr, const float* __restrict__ dmi,
                             __hip_bfloat16* __restrict__ w1p, __hip_bfloat16* __restrict__ w2p,
                             __hip_bfloat16* __restrict__ encp, __hip_bfloat16* __restrict__ decp) {
  int idx = blockIdx.x * 256 + threadIdx.x;   // 155648
  if (idx < 65536) {
    int j = idx & 7, lane = (idx >> 3) & 63, kt = (idx >> 9) & 3, nt = idx >> 11;
    int k = kt * 32 + (lane >> 4) * 8 + j;
    int n = nt * 16 + (lane & 15);
    w1p[idx] = __float2bfloat16(w1[k * 512 + n]);
  } else if (idx < 131072) {
    int i2 = idx - 65536;
    int j = i2 & 7, lane = (i2 >> 3) & 63, kt = (i2 >> 9) & 15, nt = i2 >> 13;
    int k = kt * 32 + (lane >> 4) * 8 + j;
    int n = nt * 16 + (lane & 15);
    w2p[i2] = __float2bfloat16(w2[k * 128 + n]);
  } else if (idx < 147456) {
    int i2 = idx - 131072;                    // enc: nt<8, kt<4
    int j = i2 & 7, lane = (i2 >> 3) & 63, kt = (i2 >> 9) & 3, nt = i2 >> 11;
    int k = kt * 32 + (lane >> 4) * 8 + j;
    int n = nt * 16 + (lane & 15);
    float v;
    if (k < 64) v = (n < 64) ? er[k * 64 + n] : ei[k * 64 + (n - 64)];
    else        v = (n < 64) ? -ei[(k - 64) * 64 + n] : er[(k - 64) * 64 + (n - 64)];
    encp[i2] = __float2bfloat16(v);
  } else {
    int i2 = idx - 147456;                    // dec: nt<4, kt<4
    int j = i2 & 7, lane = (i2 >> 3) & 63, kt = (i2 >> 9) & 3, nt = i2 >> 11;
    int k = kt * 32 + (lane >> 4) * 8 + j;
    int n = nt * 16 + (lane & 15);
    float v = (k < 64) ? dmr[k * 64 + n] : -dmi[(k - 64) * 64 + n];
    decp[i2] = __float2bfloat16(v);
  }
}

// ---------------------------------------------------------------- temporal LN + encode GEMM
// block: 32 tokens of one bt. LN over 128 ch, then A(32x128) @ Benc(128x128) -> x_eigen bf16 planes
__global__ __launch_bounds__(256) void k_ln_enc(
    const float* __restrict__ xsr, const float* __restrict__ xsi,
    const float* __restrict__ lng, const float* __restrict__ lnb,
    const __hip_bfloat16* __restrict__ encp,
    __hip_bfloat16* __restrict__ xer, __hip_bfloat16* __restrict__ xei) {
  __shared__ __bf16 la[32 * 136];            // 8704 B; reused as bf16 out [128][34]
  __shared__ float red_s[8][33], red_ss[8][33];
  int blk = blockIdx.x;                      // bt*128 + hwtile
  int bt = blk >> 7;
  int hw0 = (blk & 127) << 5;
  int tid = threadIdx.x;
  int lane = tid & 63, wave = tid >> 6;
  int lc = lane & 15, quad = lane >> 4;
  int tok = tid & 31, cg = tid >> 5;
  // ---- stage (registers) + LN stats ----
  float v[16];
  float s = 0.f, ss = 0.f;
#pragma unroll
  for (int it = 0; it < 16; ++it) {
    int c = it * 8 + cg;
    const float* src = (c < 64) ? (xsr + ((size_t)(bt * 64 + c)) * NHW)
                                : (xsi + ((size_t)(bt * 64 + c - 64)) * NHW);
    v[it] = src[hw0 + tok];
    s += v[it]; ss += v[it] * v[it];
  }
  red_s[cg][tok] = s; red_ss[cg][tok] = ss;
  __syncthreads();
  float S = 0.f, SS = 0.f;
#pragma unroll
  for (int k = 0; k < 8; ++k) { S += red_s[k][tok]; SS += red_ss[k][tok]; }
  float mean = S * (1.0f / 128.0f);
  float rstd = rsqrtf(SS * (1.0f / 128.0f) - mean * mean + 1e-5f);
#pragma unroll
  for (int it = 0; it < 16; ++it) {
    int c = it * 8 + cg;
    la[tok * 136 + c] = (__bf16)((v[it] - mean) * rstd * lng[c] + lnb[c]);
  }
  __syncthreads();
  // ---- GEMM: wave owns 32 N-cols (2 nt), 2 mt ----
  f32x4 acc[2][2];
#pragma unroll
  for (int m = 0; m < 2; ++m)
#pragma unroll
    for (int n = 0; n < 2; ++n) acc[m][n] = (f32x4){0.f, 0.f, 0.f, 0.f};
#pragma unroll
  for (int kt = 0; kt < 4; ++kt) {
    bf16x8 a0 = *(const bf16x8*)&la[lc * 136 + kt * 32 + quad * 8];
    bf16x8 a1 = *(const bf16x8*)&la[(lc + 16) * 136 + kt * 32 + quad * 8];
#pragma unroll
    for (int n = 0; n < 2; ++n) {
      int ntg = wave * 2 + n;
      bf16x8 b = *(const bf16x8*)(const void*)(encp + (((size_t)ntg * 4 + kt) * 64 + lane) * 8);
      acc[0][n] = __builtin_amdgcn_mfma_f32_16x16x32_bf16(a0, b, acc[0][n], 0, 0, 0);
      acc[1][n] = __builtin_amdgcn_mfma_f32_16x16x32_bf16(a1, b, acc[1][n], 0, 0, 0);
    }
  }
  __syncthreads();                           // la reads done; reuse as out staging
  __bf16* lo = la;                           // [128][34] bf16 = 4352 elems (exact fit)
#pragma unroll
  for (int n = 0; n < 2; ++n) {
    int c = (wave * 2 + n) * 16 + lc;
#pragma unroll
    for (int m = 0; m < 2; ++m)
#pragma unroll
      for (int r = 0; r < 4; ++r)
        lo[c * 34 + m * 16 + quad * 4 + r] = (__bf16)acc[m][n][r];
  }
  __syncthreads();
  // ---- coalesced plane writes (4B per lane) ----
  {
    int tokh = tid & 15, cc = tid >> 4;      // cc 0..15
#pragma unroll
    for (int it = 0; it < 8; ++it) {
      int c = it * 16 + cc;
      __hip_bfloat16* dst = (c < 64) ? xer : xei;
      size_t ob = ((size_t)(bt * 64 + (c & 63))) * NHW + hw0 + tokh * 2;
      *(unsigned int*)((void*)(dst + ob)) =
          *(const unsigned int*)((const void*)(lo + c * 34 + tokh * 2));
    }
  }
}

// ---------------------------------------------------------------- diagonal ZOH scan (in-place over x_eigen)
__global__ __launch_bounds__(256) void k_scan(
    __hip_bfloat16* xer, __hip_bfloat16* xei,
    const float* __restrict__ lam_r, const float* __restrict__ lam_i,
    const float* __restrict__ dtv) {
  int idx = blockIdx.x * 256 + threadIdx.x;   // B*64*NHW = 1048576
  int hw = idx & 4095;
  int e = (idx >> 12) & 63;
  int b = idx >> 18;
  float lrv = lam_r[e], liv = lam_i[e];
  float dtb = dtv[b];
  float mg = __expf(lrv * dtb);
  float sn, cs;
  __sincosf(liv * dtb, &sn, &cs);
  float der = mg * cs, dei = mg * sn;
  float nr = der - 1.0f, ni = dei;
  float dn = 1.0f / (lrv * lrv + liv * liv);
  float forr = (nr * lrv + ni * liv) * dn;
  float fori = (ni * lrv - nr * liv) * dn;
  float hr = 0.f, hi = 0.f;
  size_t base = ((size_t)(b * NT * ND + e)) * NHW + hw;
  for (int t = 0; t < NT; ++t) {
    size_t off = base + (size_t)t * ND * NHW;
    float ur = __bfloat162float(xer[off]);
    float ui = __bfloat162float(xei[off]);
    float h0r = hr, h0i = hi;
    hr = h0r * der - h0i * dei + ur * forr - ui * fori;
    hi = h0r * dei + h0i * der + ur * fori + ui * forr;
    xer[off] = __float2bfloat16(hr);
    xei[off] = __float2bfloat16(hi);
  }
}

// ---------------------------------------------------------------- decode GEMM + residual add into xs_r
__global__ __launch_bounds__(256) void k_dec(
    float* __restrict__ xsr,
    const __hip_bfloat16* __restrict__ her, const __hip_bfloat16* __restrict__ hei,
    const __hip_bfloat16* __restrict__ decp) {
  __shared__ __bf16 lh2[32 * 136];           // 8704 B; reused as fp32 lo[64][33] (8448 B)
  int blk = blockIdx.x;                      // bt*128 + hwtile
  int bt = blk >> 7;
  int hw0 = (blk & 127) << 5;
  int tid = threadIdx.x;
  int lane = tid & 63, wave = tid >> 6;
  int lc = lane & 15, quad = lane >> 4;
  {
    int tok = tid & 31, cg = tid >> 5;
#pragma unroll
    for (int it = 0; it < 16; ++it) {
      int c = it * 8 + cg;
      const __hip_bfloat16* src = (c < 64) ? (her + ((size_t)(bt * 64 + c)) * NHW)
                                           : (hei + ((size_t)(bt * 64 + c - 64)) * NHW);
      lh2[tok * 136 + c] = ((const __bf16*)src)[hw0 + tok];
    }
  }
  __syncthreads();
  // ---- GEMM: out[32][64], wave owns 16 cols ----
  f32x4 acc[2];
  acc[0] = (f32x4){0.f, 0.f, 0.f, 0.f};
  acc[1] = (f32x4){0.f, 0.f, 0.f, 0.f};
#pragma unroll
  for (int kt = 0; kt < 4; ++kt) {
    bf16x8 a0 = *(const bf16x8*)&lh2[lc * 136 + kt * 32 + quad * 8];
    bf16x8 a1 = *(const bf16x8*)&lh2[(lc + 16) * 136 + kt * 32 + quad * 8];
    bf16x8 b = *(const bf16x8*)(const void*)(decp + (((size_t)wave * 4 + kt) * 64 + lane) * 8);
    acc[0] = __builtin_amdgcn_mfma_f32_16x16x32_bf16(a0, b, acc[0], 0, 0, 0);
    acc[1] = __builtin_amdgcn_mfma_f32_16x16x32_bf16(a1, b, acc[1], 0, 0, 0);
  }
  __syncthreads();                           // lh2 reads done; reuse as fp32 staging
  float* lo = (float*)lh2;
  {
    int c = wave * 16 + lc;
#pragma unroll
    for (int m = 0; m < 2; ++m)
#pragma unroll
      for (int r = 0; r < 4; ++r)
        lo[c * 33 + m * 16 + quad * 4 + r] = acc[m][r];
  }
  __syncthreads();
  {
    int tok = tid & 31, cg = tid >> 5;
#pragma unroll
    for (int it = 0; it < 8; ++it) {
      int c = it * 8 + cg;
      size_t off = ((size_t)(bt * 64 + c)) * NHW + hw0 + tok;
      xsr[off] += lo[c * 33 + tok];
    }
  }
}

// ---------------------------------------------------------------- channel MLP via MFMA
__global__ __launch_bounds__(256, 3) void k_mlp_mfma(
    const float* __restrict__ xsr, const float* __restrict__ xsi,
    const __hip_bfloat16* __restrict__ w1p, const __hip_bfloat16* __restrict__ w2p,
    const float* __restrict__ b1, const float* __restrict__ b2,
    float* __restrict__ out) {
  __shared__ __bf16 lf[32 * 136];          // f bf16, row stride 136
  __shared__ __bf16 lh[32 * 520];          // h1 bf16, row stride 520 (reused as fp32 out[128][33])
  float* lo = (float*)lh;
  int blk = blockIdx.x;                    // 8192 = bt*128 + hwtile
  int bt = blk >> 7;
  int hw0 = (blk & 127) << 5;
  int tid = threadIdx.x;
  int lane = tid & 63, wave = tid >> 6;
  int lc = lane & 15, quad = lane >> 4;
  {
    int tok = tid & 31, cg = tid >> 5;
#pragma unroll
    for (int it = 0; it < 16; ++it) {
      int c = it * 8 + cg;
      const float* src = (c < 64) ? (xsr + ((size_t)(bt * 64 + c)) * NHW)
                                  : (xsi + ((size_t)(bt * 64 + c - 64)) * NHW);
      lf[tok * 136 + c] = (__bf16)src[hw0 + tok];
    }
  }
  __syncthreads();
  f32x4 acc[2][8];
#pragma unroll
  for (int mt = 0; mt < 2; ++mt)
#pragma unroll
    for (int nt = 0; nt < 8; ++nt) acc[mt][nt] = (f32x4){0.f, 0.f, 0.f, 0.f};
#pragma unroll
  for (int kt = 0; kt < 4; ++kt) {
    bf16x8 a0 = *(const bf16x8*)&lf[lc * 136 + kt * 32 + quad * 8];
    bf16x8 a1 = *(const bf16x8*)&lf[(lc + 16) * 136 + kt * 32 + quad * 8];
    const __hip_bfloat16* wp = w1p + (((size_t)(wave * 8) * 4 + kt) * 64 + lane) * 8;
#pragma unroll
    for (int nt = 0; nt < 8; ++nt) {
      bf16x8 b = *(const bf16x8*)(const void*)(wp + (size_t)nt * (4 * 64 * 8));
      acc[0][nt] = __builtin_amdgcn_mfma_f32_16x16x32_bf16(a0, b, acc[0][nt], 0, 0, 0);
      acc[1][nt] = __builtin_amdgcn_mfma_f32_16x16x32_bf16(a1, b, acc[1][nt], 0, 0, 0);
    }
  }
#pragma unroll
  for (int nt = 0; nt < 8; ++nt) {
    int col = wave * 128 + nt * 16 + lc;
    float bb = b1[col];
#pragma unroll
    for (int mt = 0; mt < 2; ++mt)
#pragma unroll
      for (int r = 0; r < 4; ++r) {
        float x = acc[mt][nt][r] + bb;
        float y = 0.7978845608f * (x + 0.044715f * x * x * x);
        float e = __expf(2.0f * y);
        float th = 1.0f - 2.0f / (e + 1.0f);
        float gv = 0.5f * x * (1.0f + th);
        lh[(mt * 16 + quad * 4 + r) * 520 + col] = (__bf16)gv;
      }
  }
  __syncthreads();
  f32x4 acc2[2][2];
#pragma unroll
  for (int mt = 0; mt < 2; ++mt)
#pragma unroll
    for (int n = 0; n < 2; ++n) acc2[mt][n] = (f32x4){0.f, 0.f, 0.f, 0.f};
#pragma unroll
  for (int kt = 0; kt < 16; ++kt) {
    bf16x8 a0 = *(const bf16x8*)&lh[lc * 520 + kt * 32 + quad * 8];
    bf16x8 a1 = *(const bf16x8*)&lh[(lc + 16) * 520 + kt * 32 + quad * 8];
#pragma unroll
    for (int n = 0; n < 2; ++n) {
      bf16x8 b = *(const bf16x8*)(const void*)(w2p + (((size_t)(wave * 2 + n) * 16 + kt) * 64 + lane) * 8);
      acc2[0][n] = __builtin_amdgcn_mfma_f32_16x16x32_bf16(a0, b, acc2[0][n], 0, 0, 0);
      acc2[1][n] = __builtin_amdgcn_mfma_f32_16x16x32_bf16(a1, b, acc2[1][n], 0, 0, 0);
    }
  }
  __syncthreads();
#pragma unroll
  for (int n = 0; n < 2; ++n) {
    int c = wave * 32 + n * 16 + lc;
    float bb = b2[c];
#pragma unroll
    for (int mt = 0; mt < 2; ++mt)
#pragma unroll
      for (int r = 0; r < 4; ++r)
        lo[c * 33 + mt * 16 + quad * 4 + r] = acc2[mt][n][r] + bb;
  }
  __syncthreads();
  {
    int tok = tid & 31, cg = tid >> 5;
#pragma unroll
    for (int it = 0; it < 16; ++it) {
      int c = it * 8 + cg;
      const float* src = (c < 64) ? (xsr + ((size_t)(bt * 64 + c)) * NHW)
                                  : (xsi + ((size_t)(bt * 64 + c - 64)) * NHW);
      out[((size_t)(bt * 128 + c)) * NHW + hw0 + tok] = lo[c * 33 + tok] + src[hw0 + tok];
    }
  }
}

// ---------------------------------------------------------------- launch
extern "C" void kernel_launch(void* const* d_in, const int* in_sizes, int n_in,
                              void* d_out, int out_size, void* d_ws, size_t ws_size,
                              hipStream_t stream) {
  const float* x_r    = (const float*)d_in[0];
  const float* x_i    = (const float*)d_in[1];
  const float* dt     = (const float*)d_in[2];
  const float* ln_s_g = (const float*)d_in[3];
  const float* ln_s_b = (const float*)d_in[4];
  const float* conv_w = (const float*)d_in[5];
  const float* conv_b = (const float*)d_in[6];
  const float* spec_wr= (const float*)d_in[7];
  const float* spec_wi= (const float*)d_in[8];
  const float* gate   = (const float*)d_in[9];
  const float* ln_t_g = (const float*)d_in[10];
  const float* ln_t_b = (const float*)d_in[11];
  const float* lam_r  = (const float*)d_in[12];
  const float* lam_i  = (const float*)d_in[13];
  const float* enc_r  = (const float*)d_in[14];
  const float* enc_i  = (const float*)d_in[15];
  const float* dec_r  = (const float*)d_in[16];
  const float* dec_i  = (const float*)d_in[17];
  const float* p_w1   = (const float*)d_in[18];
  const float* p_b1   = (const float*)d_in[19];
  const float* p_w2   = (const float*)d_in[20];
  const float* p_b2   = (const float*)d_in[21];

  float* ws   = (float*)d_ws;
  float* xs_r = ws;                       // N fp32
  float* xs_i = ws + (size_t)NTOT;        // N fp32
  float* sbr  = ws + (size_t)2 * NTOT;    // D*HW fp32
  float* sbi  = sbr + (size_t)ND * NHW;
  __hip_bfloat16* cl_r = (__hip_bfloat16*)(sbi + (size_t)ND * NHW);  // N bf16
  __hip_bfloat16* cl_i = cl_r + (size_t)NTOT;                        // N bf16
  // packed weights live in the sbr/sbi region (dead after k_fft_combine): 304 KB of 2 MB
  __hip_bfloat16* sbpack = (__hip_bfloat16*)sbr;
  __hip_bfloat16* w1p  = sbpack;              // 65536
  __hip_bfloat16* w2p  = sbpack + 65536;      // 65536
  __hip_bfloat16* encp = sbpack + 131072;     // 16384
  __hip_bfloat16* decp = sbpack + 147456;     // 8192
  // packed conv weights live in d_out (dead until k_mlp_mfma writes it)
  __hip_bfloat16* wcp = (__hip_bfloat16*)d_out;   // 147456 bf16

  k_spec_reorder<<<1024, 256, 0, stream>>>(spec_wr, spec_wi, sbr, sbi);
  k_wconv_repack<<<576, 256, 0, stream>>>(conv_w, wcp);
  k_ln<<<1024, 256, 0, stream>>>(x_r, x_i, ln_s_g, ln_s_b, xs_r, xs_i);
  k_conv_mfma<<<4096, 256, 0, stream>>>(xs_r, xs_i, wcp, conv_b, cl_r, cl_i);
  k_fft_combine<<<4096, 256, 0, stream>>>(xs_r, xs_i, cl_r, cl_i, sbr, sbi, x_r, x_i, gate);
  // sbr/sbi and cl_r/cl_i are now dead -> repack weights, reuse cl for x_eigen/h
  k_repack_all<<<608, 256, 0, stream>>>(p_w1, p_w2, enc_r, enc_i, dec_r, dec_i,
                                        w1p, w2p, encp, decp);
  k_ln_enc<<<8192, 256, 0, stream>>>(xs_r, xs_i, ln_t_g, ln_t_b, encp, cl_r, cl_i);
  k_scan<<<4096, 256, 0, stream>>>(cl_r, cl_i, lam_r, lam_i, dt);
  k_dec<<<8192, 256, 0, stream>>>(xs_r, cl_r, cl_i, decp);
  k_mlp_mfma<<<8192, 256, 0, stream>>>(xs_r, xs_i, w1p, w2p, p_b1, p_b2, (float*)d_out);
}

// Round 3
// 930.569 us; speedup vs baseline: 2.5975x; 1.0110x over previous
//
#include <hip/hip_runtime.h>
#include <hip/hip_bf16.h>

#define NB 4
#define NT 16
#define ND 64
#define NHW 4096
#define NTOT (NB*NT*ND*NHW)   // 16,777,216 per plane

typedef __attribute__((ext_vector_type(8))) __bf16 bf16x8;
typedef __attribute__((ext_vector_type(4))) float f32x4;

// ---------------------------------------------------------------- spec reorder
__global__ void k_spec_reorder(const float* __restrict__ wr, const float* __restrict__ wi,
                               float* __restrict__ outr, float* __restrict__ outi) {
  int idx = blockIdx.x * 256 + threadIdx.x;      // D*HW = 262144
  int d = idx >> 12;
  int rc = idx & 4095;
  int r = rc >> 6, c = rc & 63;
  int br = __brev((unsigned)r) >> 26;
  int bc = __brev((unsigned)c) >> 26;
  int src = (d << 12) + (br << 6) + bc;
  outr[idx] = wr[src];
  outi[idx] = wi[src];
}

// ---------------------------------------------------------------- complex LN (spatial)
__global__ void k_ln(const float* __restrict__ xr, const float* __restrict__ xi,
                     const float* __restrict__ g, const float* __restrict__ b,
                     float* __restrict__ outr, float* __restrict__ outi) {
  int pos = blockIdx.x * 256 + threadIdx.x;      // B*T*HW = 262144
  int bt = pos >> 12;
  int hw = pos & 4095;
  size_t base = (size_t)bt * ND * NHW + hw;
  float s = 0.f, ss = 0.f;
  for (int d = 0; d < ND; ++d) {
    float r = xr[base + (size_t)d * NHW];
    float im = xi[base + (size_t)d * NHW];
    s += r + im; ss += r * r + im * im;
  }
  float mean = s * (1.0f / 128.0f);
  float var = ss * (1.0f / 128.0f) - mean * mean;
  float rstd = rsqrtf(var + 1e-5f);
  for (int d = 0; d < ND; ++d) {
    float r = xr[base + (size_t)d * NHW];
    float im = xi[base + (size_t)d * NHW];
    outr[base + (size_t)d * NHW] = (r - mean) * rstd * g[d] + b[d];
    outi[base + (size_t)d * NHW] = (im - mean) * rstd * g[64 + d] + b[64 + d];
  }
}

// ---------------------------------------------------------------- conv weight repack
__global__ void k_wconv_repack(const float* __restrict__ w, __hip_bfloat16* __restrict__ wcp) {
  int idx = blockIdx.x * 256 + threadIdx.x;   // 147456 = 9*8*4*64*8
  int j = idx & 7;
  int lane = (idx >> 3) & 63;
  int kt = (idx >> 9) & 3;
  int nt = (idx >> 11) & 7;
  int tap = idx >> 14;
  int ic = kt * 32 + (lane >> 4) * 8 + j;
  int oc = nt * 16 + (lane & 15);
  wcp[idx] = __float2bfloat16(w[((size_t)(oc * 128 + ic)) * 9 + tap]);
}

// ---------------------------------------------------------------- 3x3 conv via MFMA (implicit GEMM)
__global__ __launch_bounds__(256) void k_conv_mfma(
    const float* __restrict__ xsr, const float* __restrict__ xsi,
    const __hip_bfloat16* __restrict__ wcp, const float* __restrict__ bias,
    __hip_bfloat16* __restrict__ cr, __hip_bfloat16* __restrict__ ci) {
  __shared__ __align__(16) __bf16 lin[3 * 66 * 128];   // 50688 B
  int blk = blockIdx.x;            // bt*64 + y
  int y = blk & 63;
  int bt = blk >> 6;
  int tid = threadIdx.x;
  int lane = tid & 63, wave = tid >> 6;
  int lc = lane & 15, quad = lane >> 4;

  for (int i = tid; i < 48 * 66; i += 256) {
    int p = i / 66;                 // p = ky*16 + icg
    int pos = i - p * 66;
    int ky = p >> 4, icg = p & 15;
    int gy = y + ky - 1, gx = pos - 1;
    float vals[8];
#pragma unroll
    for (int k = 0; k < 8; ++k) vals[k] = 0.f;
    if (gy >= 0 && gy < 64 && gx >= 0 && gx < 64) {
      const float* src = (icg < 8) ? xsr : xsi;
      size_t pbase = ((size_t)(bt * 64 + (icg & 7) * 8)) * NHW + gy * 64 + gx;
#pragma unroll
      for (int k = 0; k < 8; ++k) vals[k] = src[pbase + (size_t)k * NHW];
    }
    bf16x8 v;
#pragma unroll
    for (int k = 0; k < 8; ++k) v[k] = (__bf16)vals[k];
    int elem = ((ky * 66 + pos) * 128 + icg * 8) ^ ((pos & 7) << 3);
    *(bf16x8*)(lin + elem) = v;
  }
  __syncthreads();

  int mt0 = (wave >> 1) * 2;       // 0 or 2
  int ocb = (wave & 1) * 4;        // n-tile base: 0 or 4
  f32x4 acc[2][4];
#pragma unroll
  for (int m = 0; m < 2; ++m)
#pragma unroll
    for (int n = 0; n < 4; ++n) acc[m][n] = (f32x4){0.f, 0.f, 0.f, 0.f};

  for (int ky = 0; ky < 3; ++ky) {
#pragma unroll
    for (int kt = 0; kt < 4; ++kt) {
      bf16x8 a[3][2];
#pragma unroll
      for (int kx = 0; kx < 3; ++kx)
#pragma unroll
        for (int m = 0; m < 2; ++m) {
          int pos = (mt0 + m) * 16 + lc + kx;
          int elem = ((ky * 66 + pos) * 128 + kt * 32 + quad * 8) ^ ((pos & 7) << 3);
          a[kx][m] = *(const bf16x8*)(lin + elem);
        }
#pragma unroll
      for (int kx = 0; kx < 3; ++kx) {
        const __hip_bfloat16* wp =
            wcp + ((((size_t)(ky * 3 + kx) * 8 + ocb) * 4 + kt) * 64 + lane) * 8;
#pragma unroll
        for (int n = 0; n < 4; ++n) {
          bf16x8 b = *(const bf16x8*)(const void*)(wp + (size_t)n * (4 * 64 * 8));
#pragma unroll
          for (int m = 0; m < 2; ++m)
            acc[m][n] = __builtin_amdgcn_mfma_f32_16x16x32_bf16(a[kx][m], b, acc[m][n], 0, 0, 0);
        }
      }
    }
  }
  __syncthreads();

  __bf16* lout = lin;
#pragma unroll
  for (int n = 0; n < 4; ++n) {
    int oc = (ocb + n) * 16 + lc;
    float bb = bias[oc];
#pragma unroll
    for (int m = 0; m < 2; ++m)
#pragma unroll
      for (int r = 0; r < 4; ++r)
        lout[oc * 66 + (mt0 + m) * 16 + quad * 4 + r] = (__bf16)(acc[m][n][r] + bb);
  }
  __syncthreads();

  {
    int colh = (lane & 31) * 2;
    int ocl = lane >> 5;
#pragma unroll
    for (int it = 0; it < 16; ++it) {
      int oc = it * 8 + wave * 2 + ocl;
      __hip_bfloat16* dst = (oc < 64) ? cr : ci;
      size_t ob = ((size_t)(bt * 64 + (oc & 63))) * NHW + y * 64 + colh;
      *(unsigned int*)((void*)(dst + ob)) =
          *(const unsigned int*)((const void*)(lout + oc * 66 + colh));
    }
  }
}

// ---------------------------------------------------------------- FFT64 via shfl, register twiddles
// twiddles depend only on (lane, stage): tc[st]=cos(pi*j/m), ts[st]=-sin(pi*j/m), m=32>>st, j=lane&(m-1)
__device__ __forceinline__ void fft64_fwd_tw(float& re, float& im, int lane,
                                             const float* tc, const float* ts) {
#pragma unroll
  for (int st = 0; st < 6; ++st) {
    int m = 32 >> st;
    float pr = __shfl_xor(re, m, 64);
    float pi = __shfl_xor(im, m, 64);
    float c = tc[st], s = ts[st];
    if (lane & m) {
      float tr = pr - re, ti = pi - im;
      re = tr * c - ti * s;
      im = tr * s + ti * c;
    } else { re += pr; im += pi; }
  }
}
__device__ __forceinline__ void fft64_inv_tw(float& re, float& im, int lane,
                                             const float* tc, const float* ts) {
#pragma unroll
  for (int st = 5; st >= 0; --st) {
    int m = 32 >> st;
    float c = tc[st], s = -ts[st];
    float pr = __shfl_xor(re, m, 64);
    float pi = __shfl_xor(im, m, 64);
    if (lane & m) {
      float wr = re * c - im * s, wi = re * s + im * c;
      re = pr - wr; im = pi - wi;
    } else {
      float wr = pr * c - pi * s, wi = pr * s + pi * c;
      re += wr; im += wi;
    }
  }
}

__global__ __launch_bounds__(256) void k_fft_combine(
    float* xsr, float* xsi,
    const __hip_bfloat16* __restrict__ cr, const __hip_bfloat16* __restrict__ ci,
    const float* __restrict__ sbr, const float* __restrict__ sbi,
    const float* __restrict__ x0r, const float* __restrict__ x0i,
    const float* __restrict__ gate) {
  __shared__ float lr[64 * 65], li[64 * 65];
  int slice = blockIdx.x;                      // bt*64 + d
  int d = slice & 63;
  size_t base = (size_t)slice * NHW;
  int lane = threadIdx.x & 63, wv = threadIdx.x >> 6;
  float g = gate[0];
  float tc[6], ts[6];
#pragma unroll
  for (int st = 0; st < 6; ++st) {
    int m = 32 >> st;
    float ang = -3.14159265358979f * (float)(lane & (m - 1)) / (float)m;
    __sincosf(ang, &ts[st], &tc[st]);
  }
  for (int r = wv; r < 64; r += 4) {
    float re = xsr[base + r * 64 + lane];
    float im = xsi[base + r * 64 + lane];
    fft64_fwd_tw(re, im, lane, tc, ts);
    lr[r * 65 + lane] = re; li[r * 65 + lane] = im;
  }
  __syncthreads();
  for (int c = wv; c < 64; c += 4) {
    float re = lr[lane * 65 + c], im = li[lane * 65 + c];
    fft64_fwd_tw(re, im, lane, tc, ts);
    lr[lane * 65 + c] = re; li[lane * 65 + c] = im;
  }
  __syncthreads();
  for (int r = wv; r < 64; r += 4) {
    float re = lr[r * 65 + lane], im = li[r * 65 + lane];
    float sr = sbr[(size_t)d * NHW + r * 64 + lane];
    float si = sbi[(size_t)d * NHW + r * 64 + lane];
    float nr = re * sr - im * si, ni = re * si + im * sr;
    fft64_inv_tw(nr, ni, lane, tc, ts);
    lr[r * 65 + lane] = nr * (1.0f / 64.0f);
    li[r * 65 + lane] = ni * (1.0f / 64.0f);
  }
  __syncthreads();
  for (int c = wv; c < 64; c += 4) {
    float re = lr[lane * 65 + c], im = li[lane * 65 + c];
    fft64_inv_tw(re, im, lane, tc, ts);
    lr[lane * 65 + c] = re * (1.0f / 64.0f);
    li[lane * 65 + c] = im * (1.0f / 64.0f);
  }
  __syncthreads();
  for (int r = wv; r < 64; r += 4) {
    size_t off = base + r * 64 + lane;
    float spr = lr[r * 65 + lane], spi = li[r * 65 + lane];
    float outr = g * __bfloat162float(cr[off]) + (1.f - g) * spr + x0r[off];
    float outi = g * __bfloat162float(ci[off]) + (1.f - g) * spi + x0i[off];
    xsr[off] = outr; xsi[off] = outi;
  }
}

// ---------------------------------------------------------------- all weight repacks (bf16, MFMA B-fragment order)
__global__ void k_repack_all(const float* __restrict__ w1, const float* __restrict__ w2,
                             const float* __restrict__ er, const float* __restrict__ ei,
                             const float* __restrict__ dmr, const float* __restrict__ dmi,
                             __hip_bfloat16* __restrict__ w1p, __hip_bfloat16* __restrict__ w2p,
                             __hip_bfloat16* __restrict__ encp, __hip_bfloat16* __restrict__ decp) {
  int idx = blockIdx.x * 256 + threadIdx.x;   // 155648
  if (idx < 65536) {
    int j = idx & 7, lane = (idx >> 3) & 63, kt = (idx >> 9) & 3, nt = idx >> 11;
    int k = kt * 32 + (lane >> 4) * 8 + j;
    int n = nt * 16 + (lane & 15);
    w1p[idx] = __float2bfloat16(w1[k * 512 + n]);
  } else if (idx < 131072) {
    int i2 = idx - 65536;
    int j = i2 & 7, lane = (i2 >> 3) & 63, kt = (i2 >> 9) & 15, nt = i2 >> 13;
    int k = kt * 32 + (lane >> 4) * 8 + j;
    int n = nt * 16 + (lane & 15);
    w2p[i2] = __float2bfloat16(w2[k * 128 + n]);
  } else if (idx < 147456) {
    int i2 = idx - 131072;                    // enc: nt<8, kt<4
    int j = i2 & 7, lane = (i2 >> 3) & 63, kt = (i2 >> 9) & 3, nt = i2 >> 11;
    int k = kt * 32 + (lane >> 4) * 8 + j;
    int n = nt * 16 + (lane & 15);
    float v;
    if (k < 64) v = (n < 64) ? er[k * 64 + n] : ei[k * 64 + (n - 64)];
    else        v = (n < 64) ? -ei[(k - 64) * 64 + n] : er[(k - 64) * 64 + (n - 64)];
    encp[i2] = __float2bfloat16(v);
  } else {
    int i2 = idx - 147456;                    // dec: nt<4, kt<4
    int j = i2 & 7, lane = (i2 >> 3) & 63, kt = (i2 >> 9) & 3, nt = i2 >> 11;
    int k = kt * 32 + (lane >> 4) * 8 + j;
    int n = nt * 16 + (lane & 15);
    float v = (k < 64) ? dmr[k * 64 + n] : -dmi[(k - 64) * 64 + n];
    decp[i2] = __float2bfloat16(v);
  }
}

// ---------------------------------------------------------------- temporal LN + encode GEMM
__global__ __launch_bounds__(256) void k_ln_enc(
    const float* __restrict__ xsr, const float* __restrict__ xsi,
    const float* __restrict__ lng, const float* __restrict__ lnb,
    const __hip_bfloat16* __restrict__ encp,
    __hip_bfloat16* __restrict__ xer, __hip_bfloat16* __restrict__ xei) {
  __shared__ __bf16 la[32 * 136];            // 8704 B; reused as bf16 out [128][34]
  __shared__ float red_s[8][33], red_ss[8][33];
  int blk = blockIdx.x;                      // bt*128 + hwtile
  int bt = blk >> 7;
  int hw0 = (blk & 127) << 5;
  int tid = threadIdx.x;
  int lane = tid & 63, wave = tid >> 6;
  int lc = lane & 15, quad = lane >> 4;
  int tok = tid & 31, cg = tid >> 5;
  float v[16];
  float s = 0.f, ss = 0.f;
#pragma unroll
  for (int it = 0; it < 16; ++it) {
    int c = it * 8 + cg;
    const float* src = (c < 64) ? (xsr + ((size_t)(bt * 64 + c)) * NHW)
                                : (xsi + ((size_t)(bt * 64 + c - 64)) * NHW);
    v[it] = src[hw0 + tok];
    s += v[it]; ss += v[it] * v[it];
  }
  red_s[cg][tok] = s; red_ss[cg][tok] = ss;
  __syncthreads();
  float S = 0.f, SS = 0.f;
#pragma unroll
  for (int k = 0; k < 8; ++k) { S += red_s[k][tok]; SS += red_ss[k][tok]; }
  float mean = S * (1.0f / 128.0f);
  float rstd = rsqrtf(SS * (1.0f / 128.0f) - mean * mean + 1e-5f);
#pragma unroll
  for (int it = 0; it < 16; ++it) {
    int c = it * 8 + cg;
    la[tok * 136 + c] = (__bf16)((v[it] - mean) * rstd * lng[c] + lnb[c]);
  }
  __syncthreads();
  f32x4 acc[2][2];
#pragma unroll
  for (int m = 0; m < 2; ++m)
#pragma unroll
    for (int n = 0; n < 2; ++n) acc[m][n] = (f32x4){0.f, 0.f, 0.f, 0.f};
#pragma unroll
  for (int kt = 0; kt < 4; ++kt) {
    bf16x8 a0 = *(const bf16x8*)&la[lc * 136 + kt * 32 + quad * 8];
    bf16x8 a1 = *(const bf16x8*)&la[(lc + 16) * 136 + kt * 32 + quad * 8];
#pragma unroll
    for (int n = 0; n < 2; ++n) {
      int ntg = wave * 2 + n;
      bf16x8 b = *(const bf16x8*)(const void*)(encp + (((size_t)ntg * 4 + kt) * 64 + lane) * 8);
      acc[0][n] = __builtin_amdgcn_mfma_f32_16x16x32_bf16(a0, b, acc[0][n], 0, 0, 0);
      acc[1][n] = __builtin_amdgcn_mfma_f32_16x16x32_bf16(a1, b, acc[1][n], 0, 0, 0);
    }
  }
  __syncthreads();
  __bf16* lo = la;
#pragma unroll
  for (int n = 0; n < 2; ++n) {
    int c = (wave * 2 + n) * 16 + lc;
#pragma unroll
    for (int m = 0; m < 2; ++m)
#pragma unroll
      for (int r = 0; r < 4; ++r)
        lo[c * 34 + m * 16 + quad * 4 + r] = (__bf16)acc[m][n][r];
  }
  __syncthreads();
  {
    int tokh = tid & 15, cc = tid >> 4;
#pragma unroll
    for (int it = 0; it < 8; ++it) {
      int c = it * 16 + cc;
      __hip_bfloat16* dst = (c < 64) ? xer : xei;
      size_t ob = ((size_t)(bt * 64 + (c & 63))) * NHW + hw0 + tokh * 2;
      *(unsigned int*)((void*)(dst + ob)) =
          *(const unsigned int*)((const void*)(lo + c * 34 + tokh * 2));
    }
  }
}

// ---------------------------------------------------------------- diagonal ZOH scan (in-place over x_eigen)
__global__ __launch_bounds__(256) void k_scan(
    __hip_bfloat16* xer, __hip_bfloat16* xei,
    const float* __restrict__ lam_r, const float* __restrict__ lam_i,
    const float* __restrict__ dtv) {
  int idx = blockIdx.x * 256 + threadIdx.x;   // B*64*NHW = 1048576
  int hw = idx & 4095;
  int e = (idx >> 12) & 63;
  int b = idx >> 18;
  float lrv = lam_r[e], liv = lam_i[e];
  float dtb = dtv[b];
  float mg = __expf(lrv * dtb);
  float sn, cs;
  __sincosf(liv * dtb, &sn, &cs);
  float der = mg * cs, dei = mg * sn;
  float nr = der - 1.0f, ni = dei;
  float dn = 1.0f / (lrv * lrv + liv * liv);
  float forr = (nr * lrv + ni * liv) * dn;
  float fori = (ni * lrv - nr * liv) * dn;
  float hr = 0.f, hi = 0.f;
  size_t base = ((size_t)(b * NT * ND + e)) * NHW + hw;
  for (int t = 0; t < NT; ++t) {
    size_t off = base + (size_t)t * ND * NHW;
    float ur = __bfloat162float(xer[off]);
    float ui = __bfloat162float(xei[off]);
    float h0r = hr, h0i = hi;
    hr = h0r * der - h0i * dei + ur * forr - ui * fori;
    hi = h0r * dei + h0i * der + ur * fori + ui * forr;
    xer[off] = __float2bfloat16(hr);
    xei[off] = __float2bfloat16(hi);
  }
}

// ---------------------------------------------------------------- decode GEMM + residual add into xs_r
__global__ __launch_bounds__(256) void k_dec(
    float* __restrict__ xsr,
    const __hip_bfloat16* __restrict__ her, const __hip_bfloat16* __restrict__ hei,
    const __hip_bfloat16* __restrict__ decp) {
  __shared__ __bf16 lh2[32 * 136];           // 8704 B; reused as fp32 lo[64][33] (8448 B)
  int blk = blockIdx.x;                      // bt*128 + hwtile
  int bt = blk >> 7;
  int hw0 = (blk & 127) << 5;
  int tid = threadIdx.x;
  int lane = tid & 63, wave = tid >> 6;
  int lc = lane & 15, quad = lane >> 4;
  {
    int tok = tid & 31, cg = tid >> 5;
#pragma unroll
    for (int it = 0; it < 16; ++it) {
      int c = it * 8 + cg;
      const __hip_bfloat16* src = (c < 64) ? (her + ((size_t)(bt * 64 + c)) * NHW)
                                           : (hei + ((size_t)(bt * 64 + c - 64)) * NHW);
      lh2[tok * 136 + c] = ((const __bf16*)src)[hw0 + tok];
    }
  }
  __syncthreads();
  f32x4 acc[2];
  acc[0] = (f32x4){0.f, 0.f, 0.f, 0.f};
  acc[1] = (f32x4){0.f, 0.f, 0.f, 0.f};
#pragma unroll
  for (int kt = 0; kt < 4; ++kt) {
    bf16x8 a0 = *(const bf16x8*)&lh2[lc * 136 + kt * 32 + quad * 8];
    bf16x8 a1 = *(const bf16x8*)&lh2[(lc + 16) * 136 + kt * 32 + quad * 8];
    bf16x8 b = *(const bf16x8*)(const void*)(decp + (((size_t)wave * 4 + kt) * 64 + lane) * 8);
    acc[0] = __builtin_amdgcn_mfma_f32_16x16x32_bf16(a0, b, acc[0], 0, 0, 0);
    acc[1] = __builtin_amdgcn_mfma_f32_16x16x32_bf16(a1, b, acc[1], 0, 0, 0);
  }
  __syncthreads();
  float* lo = (float*)lh2;
  {
    int c = wave * 16 + lc;
#pragma unroll
    for (int m = 0; m < 2; ++m)
#pragma unroll
      for (int r = 0; r < 4; ++r)
        lo[c * 33 + m * 16 + quad * 4 + r] = acc[m][r];
  }
  __syncthreads();
  {
    int tok = tid & 31, cg = tid >> 5;
#pragma unroll
    for (int it = 0; it < 8; ++it) {
      int c = it * 8 + cg;
      size_t off = ((size_t)(bt * 64 + c)) * NHW + hw0 + tok;
      xsr[off] += lo[c * 33 + tok];
    }
  }
}

// ---------------------------------------------------------------- channel MLP via MFMA
__global__ __launch_bounds__(256, 3) void k_mlp_mfma(
    const float* __restrict__ xsr, const float* __restrict__ xsi,
    const __hip_bfloat16* __restrict__ w1p, const __hip_bfloat16* __restrict__ w2p,
    const float* __restrict__ b1, const float* __restrict__ b2,
    float* __restrict__ out) {
  __shared__ __bf16 lf[32 * 136];          // f bf16, row stride 136
  __shared__ __bf16 lh[32 * 520];          // h1 bf16, row stride 520 (reused as fp32 out[128][33])
  float* lo = (float*)lh;
  int blk = blockIdx.x;                    // 8192 = bt*128 + hwtile
  int bt = blk >> 7;
  int hw0 = (blk & 127) << 5;
  int tid = threadIdx.x;
  int lane = tid & 63, wave = tid >> 6;
  int lc = lane & 15, quad = lane >> 4;
  {
    int tok = tid & 31, cg = tid >> 5;
#pragma unroll
    for (int it = 0; it < 16; ++it) {
      int c = it * 8 + cg;
      const float* src = (c < 64) ? (xsr + ((size_t)(bt * 64 + c)) * NHW)
                                  : (xsi + ((size_t)(bt * 64 + c - 64)) * NHW);
      lf[tok * 136 + c] = (__bf16)src[hw0 + tok];
    }
  }
  __syncthreads();
  f32x4 acc[2][8];
#pragma unroll
  for (int mt = 0; mt < 2; ++mt)
#pragma unroll
    for (int nt = 0; nt < 8; ++nt) acc[mt][nt] = (f32x4){0.f, 0.f, 0.f, 0.f};
#pragma unroll
  for (int kt = 0; kt < 4; ++kt) {
    bf16x8 a0 = *(const bf16x8*)&lf[lc * 136 + kt * 32 + quad * 8];
    bf16x8 a1 = *(const bf16x8*)&lf[(lc + 16) * 136 + kt * 32 + quad * 8];
    const __hip_bfloat16* wp = w1p + (((size_t)(wave * 8) * 4 + kt) * 64 + lane) * 8;
#pragma unroll
    for (int nt = 0; nt < 8; ++nt) {
      bf16x8 b = *(const bf16x8*)(const void*)(wp + (size_t)nt * (4 * 64 * 8));
      acc[0][nt] = __builtin_amdgcn_mfma_f32_16x16x32_bf16(a0, b, acc[0][nt], 0, 0, 0);
      acc[1][nt] = __builtin_amdgcn_mfma_f32_16x16x32_bf16(a1, b, acc[1][nt], 0, 0, 0);
    }
  }
#pragma unroll
  for (int nt = 0; nt < 8; ++nt) {
    int col = wave * 128 + nt * 16 + lc;
    float bb = b1[col];
#pragma unroll
    for (int mt = 0; mt < 2; ++mt)
#pragma unroll
      for (int r = 0; r < 4; ++r) {
        float x = acc[mt][nt][r] + bb;
        float y = 0.7978845608f * (x + 0.044715f * x * x * x);
        float e = __expf(2.0f * y);
        float th = 1.0f - 2.0f / (e + 1.0f);
        float gv = 0.5f * x * (1.0f + th);
        lh[(mt * 16 + quad * 4 + r) * 520 + col] = (__bf16)gv;
      }
  }
  __syncthreads();
  f32x4 acc2[2][2];
#pragma unroll
  for (int mt = 0; mt < 2; ++mt)
#pragma unroll
    for (int n = 0; n < 2; ++n) acc2[mt][n] = (f32x4){0.f, 0.f, 0.f, 0.f};
#pragma unroll
  for (int kt = 0; kt < 16; ++kt) {
    bf16x8 a0 = *(const bf16x8*)&lh[lc * 520 + kt * 32 + quad * 8];
    bf16x8 a1 = *(const bf16x8*)&lh[(lc + 16) * 520 + kt * 32 + quad * 8];
#pragma unroll
    for (int n = 0; n < 2; ++n) {
      bf16x8 b = *(const bf16x8*)(const void*)(w2p + (((size_t)(wave * 2 + n) * 16 + kt) * 64 + lane) * 8);
      acc2[0][n] = __builtin_amdgcn_mfma_f32_16x16x32_bf16(a0, b, acc2[0][n], 0, 0, 0);
      acc2[1][n] = __builtin_amdgcn_mfma_f32_16x16x32_bf16(a1, b, acc2[1][n], 0, 0, 0);
    }
  }
  __syncthreads();
#pragma unroll
  for (int n = 0; n < 2; ++n) {
    int c = wave * 32 + n * 16 + lc;
    float bb = b2[c];
#pragma unroll
    for (int mt = 0; mt < 2; ++mt)
#pragma unroll
      for (int r = 0; r < 4; ++r)
        lo[c * 33 + mt * 16 + quad * 4 + r] = acc2[mt][n][r] + bb;
  }
  __syncthreads();
  {
    int tok = tid & 31, cg = tid >> 5;
#pragma unroll
    for (int it = 0; it < 16; ++it) {
      int c = it * 8 + cg;
      const float* src = (c < 64) ? (xsr + ((size_t)(bt * 64 + c)) * NHW)
                                  : (xsi + ((size_t)(bt * 64 + c - 64)) * NHW);
      out[((size_t)(bt * 128 + c)) * NHW + hw0 + tok] = lo[c * 33 + tok] + src[hw0 + tok];
    }
  }
}

// ---------------------------------------------------------------- launch
extern "C" void kernel_launch(void* const* d_in, const int* in_sizes, int n_in,
                              void* d_out, int out_size, void* d_ws, size_t ws_size,
                              hipStream_t stream) {
  const float* x_r    = (const float*)d_in[0];
  const float* x_i    = (const float*)d_in[1];
  const float* dt     = (const float*)d_in[2];
  const float* ln_s_g = (const float*)d_in[3];
  const float* ln_s_b = (const float*)d_in[4];
  const float* conv_w = (const float*)d_in[5];
  const float* conv_b = (const float*)d_in[6];
  const float* spec_wr= (const float*)d_in[7];
  const float* spec_wi= (const float*)d_in[8];
  const float* gate   = (const float*)d_in[9];
  const float* ln_t_g = (const float*)d_in[10];
  const float* ln_t_b = (const float*)d_in[11];
  const float* lam_r  = (const float*)d_in[12];
  const float* lam_i  = (const float*)d_in[13];
  const float* enc_r  = (const float*)d_in[14];
  const float* enc_i  = (const float*)d_in[15];
  const float* dec_r  = (const float*)d_in[16];
  const float* dec_i  = (const float*)d_in[17];
  const float* p_w1   = (const float*)d_in[18];
  const float* p_b1   = (const float*)d_in[19];
  const float* p_w2   = (const float*)d_in[20];
  const float* p_b2   = (const float*)d_in[21];

  float* ws   = (float*)d_ws;
  float* xs_r = ws;                       // N fp32
  float* xs_i = ws + (size_t)NTOT;        // N fp32
  float* sbr  = ws + (size_t)2 * NTOT;    // D*HW fp32
  float* sbi  = sbr + (size_t)ND * NHW;
  __hip_bfloat16* cl_r = (__hip_bfloat16*)(sbi + (size_t)ND * NHW);  // N bf16
  __hip_bfloat16* cl_i = cl_r + (size_t)NTOT;                        // N bf16
  __hip_bfloat16* sbpack = (__hip_bfloat16*)sbr;
  __hip_bfloat16* w1p  = sbpack;              // 65536
  __hip_bfloat16* w2p  = sbpack + 65536;      // 65536
  __hip_bfloat16* encp = sbpack + 131072;     // 16384
  __hip_bfloat16* decp = sbpack + 147456;     // 8192
  __hip_bfloat16* wcp = (__hip_bfloat16*)d_out;   // 147456 bf16

  k_spec_reorder<<<1024, 256, 0, stream>>>(spec_wr, spec_wi, sbr, sbi);
  k_wconv_repack<<<576, 256, 0, stream>>>(conv_w, wcp);
  k_ln<<<1024, 256, 0, stream>>>(x_r, x_i, ln_s_g, ln_s_b, xs_r, xs_i);
  k_conv_mfma<<<4096, 256, 0, stream>>>(xs_r, xs_i, wcp, conv_b, cl_r, cl_i);
  k_fft_combine<<<4096, 256, 0, stream>>>(xs_r, xs_i, cl_r, cl_i, sbr, sbi, x_r, x_i, gate);
  k_repack_all<<<608, 256, 0, stream>>>(p_w1, p_w2, enc_r, enc_i, dec_r, dec_i,
                                        w1p, w2p, encp, decp);
  k_ln_enc<<<8192, 256, 0, stream>>>(xs_r, xs_i, ln_t_g, ln_t_b, encp, cl_r, cl_i);
  k_scan<<<4096, 256, 0, stream>>>(cl_r, cl_i, lam_r, lam_i, dt);
  k_dec<<<8192, 256, 0, stream>>>(xs_r, cl_r, cl_i, decp);
  k_mlp_mfma<<<8192, 256, 0, stream>>>(xs_r, xs_i, w1p, w2p, p_b1, p_b2, (float*)d_out);
}

// Round 4
// 814.548 us; speedup vs baseline: 2.9674x; 1.1424x over previous
//
#include <hip/hip_runtime.h>
#include <hip/hip_bf16.h>

#define NB 4
#define NT 16
#define ND 64
#define NHW 4096
#define NTOT (NB*NT*ND*NHW)   // 16,777,216 per plane

typedef __attribute__((ext_vector_type(8))) __bf16 bf16x8;
typedef __attribute__((ext_vector_type(4))) __bf16 bf16x4;
typedef __attribute__((ext_vector_type(4))) float f32x4;

// ---------------------------------------------------------------- complex LN (spatial)
__global__ void k_ln(const float* __restrict__ xr, const float* __restrict__ xi,
                     const float* __restrict__ g, const float* __restrict__ b,
                     float* __restrict__ outr, float* __restrict__ outi) {
  int pos = blockIdx.x * 256 + threadIdx.x;      // B*T*HW = 262144
  int bt = pos >> 12;
  int hw = pos & 4095;
  size_t base = (size_t)bt * ND * NHW + hw;
  float s = 0.f, ss = 0.f;
  for (int d = 0; d < ND; ++d) {
    float r = xr[base + (size_t)d * NHW];
    float im = xi[base + (size_t)d * NHW];
    s += r + im; ss += r * r + im * im;
  }
  float mean = s * (1.0f / 128.0f);
  float var = ss * (1.0f / 128.0f) - mean * mean;
  float rstd = rsqrtf(var + 1e-5f);
  for (int d = 0; d < ND; ++d) {
    float r = xr[base + (size_t)d * NHW];
    float im = xi[base + (size_t)d * NHW];
    outr[base + (size_t)d * NHW] = (r - mean) * rstd * g[d] + b[d];
    outi[base + (size_t)d * NHW] = (im - mean) * rstd * g[64 + d] + b[64 + d];
  }
}

// ---------------------------------------------------------------- conv weight repack
__global__ void k_wconv_repack(const float* __restrict__ w, __hip_bfloat16* __restrict__ wcp) {
  int idx = blockIdx.x * 256 + threadIdx.x;   // 147456 = 9*8*4*64*8
  int j = idx & 7;
  int lane = (idx >> 3) & 63;
  int kt = (idx >> 9) & 3;
  int nt = (idx >> 11) & 7;
  int tap = idx >> 14;
  int ic = kt * 32 + (lane >> 4) * 8 + j;
  int oc = nt * 16 + (lane & 15);
  wcp[idx] = __float2bfloat16(w[((size_t)(oc * 128 + ic)) * 9 + tap]);
}

// ---------------------------------------------------------------- 3x3 conv via MFMA (implicit GEMM)
__global__ __launch_bounds__(256) void k_conv_mfma(
    const float* __restrict__ xsr, const float* __restrict__ xsi,
    const __hip_bfloat16* __restrict__ wcp, const float* __restrict__ bias,
    __hip_bfloat16* __restrict__ cr, __hip_bfloat16* __restrict__ ci) {
  __shared__ __align__(16) __bf16 lin[3 * 66 * 128];   // 50688 B
  int blk = blockIdx.x;            // bt*64 + y
  int y = blk & 63;
  int bt = blk >> 6;
  int tid = threadIdx.x;
  int lane = tid & 63, wave = tid >> 6;
  int lc = lane & 15, quad = lane >> 4;

  for (int i = tid; i < 48 * 66; i += 256) {
    int p = i / 66;                 // p = ky*16 + icg
    int pos = i - p * 66;
    int ky = p >> 4, icg = p & 15;
    int gy = y + ky - 1, gx = pos - 1;
    float vals[8];
#pragma unroll
    for (int k = 0; k < 8; ++k) vals[k] = 0.f;
    if (gy >= 0 && gy < 64 && gx >= 0 && gx < 64) {
      const float* src = (icg < 8) ? xsr : xsi;
      size_t pbase = ((size_t)(bt * 64 + (icg & 7) * 8)) * NHW + gy * 64 + gx;
#pragma unroll
      for (int k = 0; k < 8; ++k) vals[k] = src[pbase + (size_t)k * NHW];
    }
    bf16x8 v;
#pragma unroll
    for (int k = 0; k < 8; ++k) v[k] = (__bf16)vals[k];
    int elem = ((ky * 66 + pos) * 128 + icg * 8) ^ ((pos & 7) << 3);
    *(bf16x8*)(lin + elem) = v;
  }
  __syncthreads();

  int mt0 = (wave >> 1) * 2;       // 0 or 2
  int ocb = (wave & 1) * 4;        // n-tile base: 0 or 4
  f32x4 acc[2][4];
#pragma unroll
  for (int m = 0; m < 2; ++m)
#pragma unroll
    for (int n = 0; n < 4; ++n) acc[m][n] = (f32x4){0.f, 0.f, 0.f, 0.f};

  for (int ky = 0; ky < 3; ++ky) {
#pragma unroll
    for (int kt = 0; kt < 4; ++kt) {
      bf16x8 a[3][2];
#pragma unroll
      for (int kx = 0; kx < 3; ++kx)
#pragma unroll
        for (int m = 0; m < 2; ++m) {
          int pos = (mt0 + m) * 16 + lc + kx;
          int elem = ((ky * 66 + pos) * 128 + kt * 32 + quad * 8) ^ ((pos & 7) << 3);
          a[kx][m] = *(const bf16x8*)(lin + elem);
        }
#pragma unroll
      for (int kx = 0; kx < 3; ++kx) {
        const __hip_bfloat16* wp =
            wcp + ((((size_t)(ky * 3 + kx) * 8 + ocb) * 4 + kt) * 64 + lane) * 8;
#pragma unroll
        for (int n = 0; n < 4; ++n) {
          bf16x8 b = *(const bf16x8*)(const void*)(wp + (size_t)n * (4 * 64 * 8));
#pragma unroll
          for (int m = 0; m < 2; ++m)
            acc[m][n] = __builtin_amdgcn_mfma_f32_16x16x32_bf16(a[kx][m], b, acc[m][n], 0, 0, 0);
        }
      }
    }
  }
  __syncthreads();

  __bf16* lout = lin;
#pragma unroll
  for (int n = 0; n < 4; ++n) {
    int oc = (ocb + n) * 16 + lc;
    float bb = bias[oc];
#pragma unroll
    for (int m = 0; m < 2; ++m)
#pragma unroll
      for (int r = 0; r < 4; ++r)
        lout[oc * 66 + (mt0 + m) * 16 + quad * 4 + r] = (__bf16)(acc[m][n][r] + bb);
  }
  __syncthreads();

  {
    int colh = (lane & 31) * 2;
    int ocl = lane >> 5;
#pragma unroll
    for (int it = 0; it < 16; ++it) {
      int oc = it * 8 + wave * 2 + ocl;
      __hip_bfloat16* dst = (oc < 64) ? cr : ci;
      size_t ob = ((size_t)(bt * 64 + (oc & 63))) * NHW + y * 64 + colh;
      *(unsigned int*)((void*)(dst + ob)) =
          *(const unsigned int*)((const void*)(lout + oc * 66 + colh));
    }
  }
}

// ---------------------------------------------------------------- DFT-by-MFMA helpers
// GEMM: C(64x128) = A(64x128, LDS bf16 stride 136) @ B(128x128, packed global bf16)
// wave w owns n-tiles {w, w+4} so each lane holds matched (real, imag) pairs.
__device__ __forceinline__ void gemm64x128(const __bf16* __restrict__ src,
                                           const __hip_bfloat16* __restrict__ bp,
                                           int lane, int lc, int quad, int w,
                                           f32x4 (&acc)[4][2]) {
#pragma unroll
  for (int m = 0; m < 4; ++m)
#pragma unroll
    for (int n = 0; n < 2; ++n) acc[m][n] = (f32x4){0.f, 0.f, 0.f, 0.f};
#pragma unroll
  for (int kt = 0; kt < 4; ++kt) {
    bf16x8 a[4];
#pragma unroll
    for (int m = 0; m < 4; ++m)
      a[m] = *(const bf16x8*)&src[(m * 16 + lc) * 136 + kt * 32 + quad * 8];
#pragma unroll
    for (int n = 0; n < 2; ++n) {
      int ntg = w + n * 4;
      bf16x8 b = *(const bf16x8*)(const void*)(bp + (((size_t)ntg * 4 + kt) * 64 + lane) * 8);
#pragma unroll
      for (int m = 0; m < 4; ++m)
        acc[m][n] = __builtin_amdgcn_mfma_f32_16x16x32_bf16(a[m], b, acc[m][n], 0, 0, 0);
    }
  }
}
// write acc transposed: value(row = m*16+quad*4+r, col-part n, colidx w*16+lc)
//   -> dst[(w*16+lc)*136 + n*64 + m*16+quad*4 + r]
__device__ __forceinline__ void store_T(__bf16* __restrict__ dst,
                                        int lc, int quad, int w, f32x4 (&acc)[4][2]) {
#pragma unroll
  for (int m = 0; m < 4; ++m)
#pragma unroll
    for (int n = 0; n < 2; ++n) {
      bf16x4 v;
#pragma unroll
      for (int r = 0; r < 4; ++r) v[r] = (__bf16)acc[m][n][r];
      *(bf16x4*)&dst[(w * 16 + lc) * 136 + n * 64 + m * 16 + quad * 4] = v;
    }
}

// ---------------------------------------------------------------- fused 2D DFT * W * IDFT + combine
// per block: one (bt,d) slice. X' = G (W o (F X F)) G, F = 64-pt DFT (symmetric), G = conj(F)/64.
// complex as [re|im] 128-wide rows with B = [[Br,Bi],[-Bi,Br]].
__global__ __launch_bounds__(256) void k_fft_mfma(
    float* xsr, float* xsi,
    const __hip_bfloat16* __restrict__ cr, const __hip_bfloat16* __restrict__ ci,
    const float* __restrict__ swr, const float* __restrict__ swi,
    const float* __restrict__ x0r, const float* __restrict__ x0i,
    const float* __restrict__ gate,
    const __hip_bfloat16* __restrict__ Fp, const __hip_bfloat16* __restrict__ Gp) {
  __shared__ __align__(16) __bf16 lA[64 * 136];   // 17408 B
  __shared__ __align__(16) __bf16 lB[64 * 136];
  int slice = blockIdx.x;                         // bt*64 + d
  int d = slice & 63;
  size_t base = (size_t)slice * NHW;
  int tid = threadIdx.x, lane = tid & 63, w = tid >> 6;
  int lc = lane & 15, quad = lane >> 4;
  float g = gate[0];

  // ---- stage X -> lA: [y][0..63]=re, [y][64..127]=im (bf16) ----
  {
    int y = tid >> 2, xo = (tid & 3) * 4;
#pragma unroll
    for (int k = 0; k < 4; ++k) {
      int x = xo + k * 16;
      float4 vr = *(const float4*)(xsr + base + y * 64 + x);
      float4 vi = *(const float4*)(xsi + base + y * 64 + x);
      bf16x4 br_, bi_;
#pragma unroll
      for (int r = 0; r < 4; ++r) { br_[r] = (__bf16)(&vr.x)[r]; bi_[r] = (__bf16)(&vi.x)[r]; }
      *(bf16x4*)&lA[y * 136 + x] = br_;
      *(bf16x4*)&lA[y * 136 + 64 + x] = bi_;
    }
  }
  __syncthreads();
  f32x4 acc[4][2];
  // ---- G1: U = X*F ; write U^T -> lB ----
  gemm64x128(lA, Fp, lane, lc, quad, w, acc);
  store_T(lB, lc, quad, w, acc);
  __syncthreads();
  // ---- G2: Y^T = U^T*F ; spectral multiply ; write Z natural -> lA ----
  gemm64x128(lB, Fp, lane, lc, quad, w, acc);
  {
    int ky = w * 16 + lc;
    const float* wrp = swr + (size_t)d * 4096 + ky * 64;
    const float* wip = swi + (size_t)d * 4096 + ky * 64;
#pragma unroll
    for (int m = 0; m < 4; ++m) {
      int kx0 = m * 16 + quad * 4;
      float4 wr4 = *(const float4*)(wrp + kx0);
      float4 wi4 = *(const float4*)(wip + kx0);
      bf16x4 zr4, zi4;
#pragma unroll
      for (int r = 0; r < 4; ++r) {
        float yr = acc[m][0][r], yi = acc[m][1][r];
        float wr = (&wr4.x)[r], wi = (&wi4.x)[r];
        zr4[r] = (__bf16)(yr * wr - yi * wi);
        zi4[r] = (__bf16)(yr * wi + yi * wr);
      }
      *(bf16x4*)&lA[ky * 136 + kx0] = zr4;
      *(bf16x4*)&lA[ky * 136 + 64 + kx0] = zi4;
    }
  }
  __syncthreads();
  // ---- G3: R = Z*G ; write R^T -> lB ----
  gemm64x128(lA, Gp, lane, lc, quad, w, acc);
  store_T(lB, lc, quad, w, acc);
  __syncthreads();
  // ---- G4: X'^T = R^T*G ; combine + store ----
  gemm64x128(lB, Gp, lane, lc, quad, w, acc);
  {
    int y = w * 16 + lc;
#pragma unroll
    for (int m = 0; m < 4; ++m) {
      int x = m * 16 + quad * 4;
      size_t off = base + y * 64 + x;
      float4 v0r = *(const float4*)(x0r + off);
      float4 v0i = *(const float4*)(x0i + off);
      bf16x4 c4r = *(const bf16x4*)((const __bf16*)cr + off);
      bf16x4 c4i = *(const bf16x4*)((const __bf16*)ci + off);
      float4 outr, outi;
#pragma unroll
      for (int r = 0; r < 4; ++r) {
        (&outr.x)[r] = g * (float)c4r[r] + (1.f - g) * acc[m][0][r] + (&v0r.x)[r];
        (&outi.x)[r] = g * (float)c4i[r] + (1.f - g) * acc[m][1][r] + (&v0i.x)[r];
      }
      *(float4*)(xsr + off) = outr;
      *(float4*)(xsi + off) = outi;
    }
  }
}

// ---------------------------------------------------------------- all weight repacks (bf16, MFMA B-fragment order)
// w1p: 128x512, w2p: 512x128, encp: 128x128, decp: 128x64, Fp/Gp: 128x128 DFT matrices
__global__ void k_repack_all(const float* __restrict__ w1, const float* __restrict__ w2,
                             const float* __restrict__ er, const float* __restrict__ ei,
                             const float* __restrict__ dmr, const float* __restrict__ dmi,
                             __hip_bfloat16* __restrict__ w1p, __hip_bfloat16* __restrict__ w2p,
                             __hip_bfloat16* __restrict__ encp, __hip_bfloat16* __restrict__ decp,
                             __hip_bfloat16* __restrict__ fp, __hip_bfloat16* __restrict__ gp) {
  int idx = blockIdx.x * 256 + threadIdx.x;   // 188416
  if (idx < 65536) {
    int j = idx & 7, lane = (idx >> 3) & 63, kt = (idx >> 9) & 3, nt = idx >> 11;
    int k = kt * 32 + (lane >> 4) * 8 + j;
    int n = nt * 16 + (lane & 15);
    w1p[idx] = __float2bfloat16(w1[k * 512 + n]);
  } else if (idx < 131072) {
    int i2 = idx - 65536;
    int j = i2 & 7, lane = (i2 >> 3) & 63, kt = (i2 >> 9) & 15, nt = i2 >> 13;
    int k = kt * 32 + (lane >> 4) * 8 + j;
    int n = nt * 16 + (lane & 15);
    w2p[i2] = __float2bfloat16(w2[k * 128 + n]);
  } else if (idx < 147456) {
    int i2 = idx - 131072;                    // enc: nt<8, kt<4
    int j = i2 & 7, lane = (i2 >> 3) & 63, kt = (i2 >> 9) & 3, nt = i2 >> 11;
    int k = kt * 32 + (lane >> 4) * 8 + j;
    int n = nt * 16 + (lane & 15);
    float v;
    if (k < 64) v = (n < 64) ? er[k * 64 + n] : ei[k * 64 + (n - 64)];
    else        v = (n < 64) ? -ei[(k - 64) * 64 + n] : er[(k - 64) * 64 + (n - 64)];
    encp[i2] = __float2bfloat16(v);
  } else if (idx < 155648) {
    int i2 = idx - 147456;                    // dec: nt<4, kt<4
    int j = i2 & 7, lane = (i2 >> 3) & 63, kt = (i2 >> 9) & 3, nt = i2 >> 11;
    int k = kt * 32 + (lane >> 4) * 8 + j;
    int n = nt * 16 + (lane & 15);
    float v = (k < 64) ? dmr[k * 64 + n] : -dmi[(k - 64) * 64 + n];
    decp[i2] = __float2bfloat16(v);
  } else if (idx < 172032) {
    int i2 = idx - 155648;                    // Fp: fwd DFT [[Fr,Fi],[-Fi,Fr]], Fr=cos, Fi=-sin
    int j = i2 & 7, lane = (i2 >> 3) & 63, kt = (i2 >> 9) & 3, nt = i2 >> 11;
    int k = kt * 32 + (lane >> 4) * 8 + j;
    int n = nt * 16 + (lane & 15);
    int p = ((k & 63) * (n & 63)) & 63;
    float sv, cv;
    __sincosf((float)p * 0.09817477042f, &sv, &cv);   // 2*pi/64
    float v = ((k < 64) == (n < 64)) ? cv : ((n >= 64) ? -sv : sv);
    fp[i2] = __float2bfloat16(v);
  } else {
    int i2 = idx - 172032;                    // Gp: inv [[Gr,Gi],[-Gi,Gr]], Gr=cos/64, Gi=+sin/64
    int j = i2 & 7, lane = (i2 >> 3) & 63, kt = (i2 >> 9) & 3, nt = i2 >> 11;
    int k = kt * 32 + (lane >> 4) * 8 + j;
    int n = nt * 16 + (lane & 15);
    int p = ((k & 63) * (n & 63)) & 63;
    float sv, cv;
    __sincosf((float)p * 0.09817477042f, &sv, &cv);
    float v = (((k < 64) == (n < 64)) ? cv : ((n >= 64) ? sv : -sv)) * 0.015625f;
    gp[i2] = __float2bfloat16(v);
  }
}

// ---------------------------------------------------------------- temporal LN + encode GEMM
__global__ __launch_bounds__(256) void k_ln_enc(
    const float* __restrict__ xsr, const float* __restrict__ xsi,
    const float* __restrict__ lng, const float* __restrict__ lnb,
    const __hip_bfloat16* __restrict__ encp,
    __hip_bfloat16* __restrict__ xer, __hip_bfloat16* __restrict__ xei) {
  __shared__ __bf16 la[32 * 136];            // 8704 B; reused as bf16 out [128][34]
  __shared__ float red_s[8][33], red_ss[8][33];
  int blk = blockIdx.x;                      // bt*128 + hwtile
  int bt = blk >> 7;
  int hw0 = (blk & 127) << 5;
  int tid = threadIdx.x;
  int lane = tid & 63, wave = tid >> 6;
  int lc = lane & 15, quad = lane >> 4;
  int tok = tid & 31, cg = tid >> 5;
  float v[16];
  float s = 0.f, ss = 0.f;
#pragma unroll
  for (int it = 0; it < 16; ++it) {
    int c = it * 8 + cg;
    const float* src = (c < 64) ? (xsr + ((size_t)(bt * 64 + c)) * NHW)
                                : (xsi + ((size_t)(bt * 64 + c - 64)) * NHW);
    v[it] = src[hw0 + tok];
    s += v[it]; ss += v[it] * v[it];
  }
  red_s[cg][tok] = s; red_ss[cg][tok] = ss;
  __syncthreads();
  float S = 0.f, SS = 0.f;
#pragma unroll
  for (int k = 0; k < 8; ++k) { S += red_s[k][tok]; SS += red_ss[k][tok]; }
  float mean = S * (1.0f / 128.0f);
  float rstd = rsqrtf(SS * (1.0f / 128.0f) - mean * mean + 1e-5f);
#pragma unroll
  for (int it = 0; it < 16; ++it) {
    int c = it * 8 + cg;
    la[tok * 136 + c] = (__bf16)((v[it] - mean) * rstd * lng[c] + lnb[c]);
  }
  __syncthreads();
  f32x4 acc[2][2];
#pragma unroll
  for (int m = 0; m < 2; ++m)
#pragma unroll
    for (int n = 0; n < 2; ++n) acc[m][n] = (f32x4){0.f, 0.f, 0.f, 0.f};
#pragma unroll
  for (int kt = 0; kt < 4; ++kt) {
    bf16x8 a0 = *(const bf16x8*)&la[lc * 136 + kt * 32 + quad * 8];
    bf16x8 a1 = *(const bf16x8*)&la[(lc + 16) * 136 + kt * 32 + quad * 8];
#pragma unroll
    for (int n = 0; n < 2; ++n) {
      int ntg = wave * 2 + n;
      bf16x8 b = *(const bf16x8*)(const void*)(encp + (((size_t)ntg * 4 + kt) * 64 + lane) * 8);
      acc[0][n] = __builtin_amdgcn_mfma_f32_16x16x32_bf16(a0, b, acc[0][n], 0, 0, 0);
      acc[1][n] = __builtin_amdgcn_mfma_f32_16x16x32_bf16(a1, b, acc[1][n], 0, 0, 0);
    }
  }
  __syncthreads();
  __bf16* lo = la;
#pragma unroll
  for (int n = 0; n < 2; ++n) {
    int c = (wave * 2 + n) * 16 + lc;
#pragma unroll
    for (int m = 0; m < 2; ++m)
#pragma unroll
      for (int r = 0; r < 4; ++r)
        lo[c * 34 + m * 16 + quad * 4 + r] = (__bf16)acc[m][n][r];
  }
  __syncthreads();
  {
    int tokh = tid & 15, cc = tid >> 4;
#pragma unroll
    for (int it = 0; it < 8; ++it) {
      int c = it * 16 + cc;
      __hip_bfloat16* dst = (c < 64) ? xer : xei;
      size_t ob = ((size_t)(bt * 64 + (c & 63))) * NHW + hw0 + tokh * 2;
      *(unsigned int*)((void*)(dst + ob)) =
          *(const unsigned int*)((const void*)(lo + c * 34 + tokh * 2));
    }
  }
}

// ---------------------------------------------------------------- diagonal ZOH scan (in-place over x_eigen)
__global__ __launch_bounds__(256) void k_scan(
    __hip_bfloat16* xer, __hip_bfloat16* xei,
    const float* __restrict__ lam_r, const float* __restrict__ lam_i,
    const float* __restrict__ dtv) {
  int idx = blockIdx.x * 256 + threadIdx.x;   // B*64*NHW = 1048576
  int hw = idx & 4095;
  int e = (idx >> 12) & 63;
  int b = idx >> 18;
  float lrv = lam_r[e], liv = lam_i[e];
  float dtb = dtv[b];
  float mg = __expf(lrv * dtb);
  float sn, cs;
  __sincosf(liv * dtb, &sn, &cs);
  float der = mg * cs, dei = mg * sn;
  float nr = der - 1.0f, ni = dei;
  float dn = 1.0f / (lrv * lrv + liv * liv);
  float forr = (nr * lrv + ni * liv) * dn;
  float fori = (ni * lrv - nr * liv) * dn;
  float hr = 0.f, hi = 0.f;
  size_t base = ((size_t)(b * NT * ND + e)) * NHW + hw;
  for (int t = 0; t < NT; ++t) {
    size_t off = base + (size_t)t * ND * NHW;
    float ur = __bfloat162float(xer[off]);
    float ui = __bfloat162float(xei[off]);
    float h0r = hr, h0i = hi;
    hr = h0r * der - h0i * dei + ur * forr - ui * fori;
    hi = h0r * dei + h0i * der + ur * fori + ui * forr;
    xer[off] = __float2bfloat16(hr);
    xei[off] = __float2bfloat16(hi);
  }
}

// ---------------------------------------------------------------- decode GEMM + residual add into xs_r
__global__ __launch_bounds__(256) void k_dec(
    float* __restrict__ xsr,
    const __hip_bfloat16* __restrict__ her, const __hip_bfloat16* __restrict__ hei,
    const __hip_bfloat16* __restrict__ decp) {
  __shared__ __bf16 lh2[32 * 136];           // 8704 B; reused as fp32 lo[64][33] (8448 B)
  int blk = blockIdx.x;                      // bt*128 + hwtile
  int bt = blk >> 7;
  int hw0 = (blk & 127) << 5;
  int tid = threadIdx.x;
  int lane = tid & 63, wave = tid >> 6;
  int lc = lane & 15, quad = lane >> 4;
  {
    int tok = tid & 31, cg = tid >> 5;
#pragma unroll
    for (int it = 0; it < 16; ++it) {
      int c = it * 8 + cg;
      const __hip_bfloat16* src = (c < 64) ? (her + ((size_t)(bt * 64 + c)) * NHW)
                                           : (hei + ((size_t)(bt * 64 + c - 64)) * NHW);
      lh2[tok * 136 + c] = ((const __bf16*)src)[hw0 + tok];
    }
  }
  __syncthreads();
  f32x4 acc[2];
  acc[0] = (f32x4){0.f, 0.f, 0.f, 0.f};
  acc[1] = (f32x4){0.f, 0.f, 0.f, 0.f};
#pragma unroll
  for (int kt = 0; kt < 4; ++kt) {
    bf16x8 a0 = *(const bf16x8*)&lh2[lc * 136 + kt * 32 + quad * 8];
    bf16x8 a1 = *(const bf16x8*)&lh2[(lc + 16) * 136 + kt * 32 + quad * 8];
    bf16x8 b = *(const bf16x8*)(const void*)(decp + (((size_t)wave * 4 + kt) * 64 + lane) * 8);
    acc[0] = __builtin_amdgcn_mfma_f32_16x16x32_bf16(a0, b, acc[0], 0, 0, 0);
    acc[1] = __builtin_amdgcn_mfma_f32_16x16x32_bf16(a1, b, acc[1], 0, 0, 0);
  }
  __syncthreads();
  float* lo = (float*)lh2;
  {
    int c = wave * 16 + lc;
#pragma unroll
    for (int m = 0; m < 2; ++m)
#pragma unroll
      for (int r = 0; r < 4; ++r)
        lo[c * 33 + m * 16 + quad * 4 + r] = acc[m][r];
  }
  __syncthreads();
  {
    int tok = tid & 31, cg = tid >> 5;
#pragma unroll
    for (int it = 0; it < 8; ++it) {
      int c = it * 8 + cg;
      size_t off = ((size_t)(bt * 64 + c)) * NHW + hw0 + tok;
      xsr[off] += lo[c * 33 + tok];
    }
  }
}

// ---------------------------------------------------------------- channel MLP via MFMA
__global__ __launch_bounds__(256, 3) void k_mlp_mfma(
    const float* __restrict__ xsr, const float* __restrict__ xsi,
    const __hip_bfloat16* __restrict__ w1p, const __hip_bfloat16* __restrict__ w2p,
    const float* __restrict__ b1, const float* __restrict__ b2,
    float* __restrict__ out) {
  __shared__ __bf16 lf[32 * 136];          // f bf16, row stride 136
  __shared__ __bf16 lh[32 * 520];          // h1 bf16, row stride 520 (reused as fp32 out[128][33])
  float* lo = (float*)lh;
  int blk = blockIdx.x;                    // 8192 = bt*128 + hwtile
  int bt = blk >> 7;
  int hw0 = (blk & 127) << 5;
  int tid = threadIdx.x;
  int lane = tid & 63, wave = tid >> 6;
  int lc = lane & 15, quad = lane >> 4;
  {
    int tok = tid & 31, cg = tid >> 5;
#pragma unroll
    for (int it = 0; it < 16; ++it) {
      int c = it * 8 + cg;
      const float* src = (c < 64) ? (xsr + ((size_t)(bt * 64 + c)) * NHW)
                                  : (xsi + ((size_t)(bt * 64 + c - 64)) * NHW);
      lf[tok * 136 + c] = (__bf16)src[hw0 + tok];
    }
  }
  __syncthreads();
  f32x4 acc[2][8];
#pragma unroll
  for (int mt = 0; mt < 2; ++mt)
#pragma unroll
    for (int nt = 0; nt < 8; ++nt) acc[mt][nt] = (f32x4){0.f, 0.f, 0.f, 0.f};
#pragma unroll
  for (int kt = 0; kt < 4; ++kt) {
    bf16x8 a0 = *(const bf16x8*)&lf[lc * 136 + kt * 32 + quad * 8];
    bf16x8 a1 = *(const bf16x8*)&lf[(lc + 16) * 136 + kt * 32 + quad * 8];
    const __hip_bfloat16* wp = w1p + (((size_t)(wave * 8) * 4 + kt) * 64 + lane) * 8;
#pragma unroll
    for (int nt = 0; nt < 8; ++nt) {
      bf16x8 b = *(const bf16x8*)(const void*)(wp + (size_t)nt * (4 * 64 * 8));
      acc[0][nt] = __builtin_amdgcn_mfma_f32_16x16x32_bf16(a0, b, acc[0][nt], 0, 0, 0);
      acc[1][nt] = __builtin_amdgcn_mfma_f32_16x16x32_bf16(a1, b, acc[1][nt], 0, 0, 0);
    }
  }
#pragma unroll
  for (int nt = 0; nt < 8; ++nt) {
    int col = wave * 128 + nt * 16 + lc;
    float bb = b1[col];
#pragma unroll
    for (int mt = 0; mt < 2; ++mt)
#pragma unroll
      for (int r = 0; r < 4; ++r) {
        float x = acc[mt][nt][r] + bb;
        float y = 0.7978845608f * (x + 0.044715f * x * x * x);
        float e = __expf(2.0f * y);
        float th = 1.0f - 2.0f / (e + 1.0f);
        float gv = 0.5f * x * (1.0f + th);
        lh[(mt * 16 + quad * 4 + r) * 520 + col] = (__bf16)gv;
      }
  }
  __syncthreads();
  f32x4 acc2[2][2];
#pragma unroll
  for (int mt = 0; mt < 2; ++mt)
#pragma unroll
    for (int n = 0; n < 2; ++n) acc2[mt][n] = (f32x4){0.f, 0.f, 0.f, 0.f};
#pragma unroll
  for (int kt = 0; kt < 16; ++kt) {
    bf16x8 a0 = *(const bf16x8*)&lh[lc * 520 + kt * 32 + quad * 8];
    bf16x8 a1 = *(const bf16x8*)&lh[(lc + 16) * 520 + kt * 32 + quad * 8];
#pragma unroll
    for (int n = 0; n < 2; ++n) {
      bf16x8 b = *(const bf16x8*)(const void*)(w2p + (((size_t)(wave * 2 + n) * 16 + kt) * 64 + lane) * 8);
      acc2[0][n] = __builtin_amdgcn_mfma_f32_16x16x32_bf16(a0, b, acc2[0][n], 0, 0, 0);
      acc2[1][n] = __builtin_amdgcn_mfma_f32_16x16x32_bf16(a1, b, acc2[1][n], 0, 0, 0);
    }
  }
  __syncthreads();
#pragma unroll
  for (int n = 0; n < 2; ++n) {
    int c = wave * 32 + n * 16 + lc;
    float bb = b2[c];
#pragma unroll
    for (int mt = 0; mt < 2; ++mt)
#pragma unroll
      for (int r = 0; r < 4; ++r)
        lo[c * 33 + mt * 16 + quad * 4 + r] = acc2[mt][n][r] + bb;
  }
  __syncthreads();
  {
    int tok = tid & 31, cg = tid >> 5;
#pragma unroll
    for (int it = 0; it < 16; ++it) {
      int c = it * 8 + cg;
      const float* src = (c < 64) ? (xsr + ((size_t)(bt * 64 + c)) * NHW)
                                  : (xsi + ((size_t)(bt * 64 + c - 64)) * NHW);
      out[((size_t)(bt * 128 + c)) * NHW + hw0 + tok] = lo[c * 33 + tok] + src[hw0 + tok];
    }
  }
}

// ---------------------------------------------------------------- launch
extern "C" void kernel_launch(void* const* d_in, const int* in_sizes, int n_in,
                              void* d_out, int out_size, void* d_ws, size_t ws_size,
                              hipStream_t stream) {
  const float* x_r    = (const float*)d_in[0];
  const float* x_i    = (const float*)d_in[1];
  const float* dt     = (const float*)d_in[2];
  const float* ln_s_g = (const float*)d_in[3];
  const float* ln_s_b = (const float*)d_in[4];
  const float* conv_w = (const float*)d_in[5];
  const float* conv_b = (const float*)d_in[6];
  const float* spec_wr= (const float*)d_in[7];
  const float* spec_wi= (const float*)d_in[8];
  const float* gate   = (const float*)d_in[9];
  const float* ln_t_g = (const float*)d_in[10];
  const float* ln_t_b = (const float*)d_in[11];
  const float* lam_r  = (const float*)d_in[12];
  const float* lam_i  = (const float*)d_in[13];
  const float* enc_r  = (const float*)d_in[14];
  const float* enc_i  = (const float*)d_in[15];
  const float* dec_r  = (const float*)d_in[16];
  const float* dec_i  = (const float*)d_in[17];
  const float* p_w1   = (const float*)d_in[18];
  const float* p_b1   = (const float*)d_in[19];
  const float* p_w2   = (const float*)d_in[20];
  const float* p_b2   = (const float*)d_in[21];

  float* ws   = (float*)d_ws;
  float* xs_r = ws;                       // N fp32
  float* xs_i = ws + (size_t)NTOT;        // N fp32
  // 2 MB pack region (former sbr/sbi; spec reorder no longer needed)
  __hip_bfloat16* sbpack = (__hip_bfloat16*)(ws + (size_t)2 * NTOT);
  __hip_bfloat16* w1p  = sbpack;              // 65536
  __hip_bfloat16* w2p  = sbpack + 65536;      // 65536
  __hip_bfloat16* encp = sbpack + 131072;     // 16384
  __hip_bfloat16* decp = sbpack + 147456;     // 8192
  __hip_bfloat16* Fp   = sbpack + 155648;     // 16384
  __hip_bfloat16* Gp   = sbpack + 172032;     // 16384
  __hip_bfloat16* cl_r = (__hip_bfloat16*)(ws + (size_t)2 * NTOT + (size_t)2 * ND * NHW);  // N bf16
  __hip_bfloat16* cl_i = cl_r + (size_t)NTOT;                                              // N bf16
  // packed conv weights live in d_out (dead until k_mlp_mfma writes it)
  __hip_bfloat16* wcp = (__hip_bfloat16*)d_out;   // 147456 bf16

  k_repack_all<<<736, 256, 0, stream>>>(p_w1, p_w2, enc_r, enc_i, dec_r, dec_i,
                                        w1p, w2p, encp, decp, Fp, Gp);
  k_wconv_repack<<<576, 256, 0, stream>>>(conv_w, wcp);
  k_ln<<<1024, 256, 0, stream>>>(x_r, x_i, ln_s_g, ln_s_b, xs_r, xs_i);
  k_conv_mfma<<<4096, 256, 0, stream>>>(xs_r, xs_i, wcp, conv_b, cl_r, cl_i);
  k_fft_mfma<<<4096, 256, 0, stream>>>(xs_r, xs_i, cl_r, cl_i, spec_wr, spec_wi,
                                       x_r, x_i, gate, Fp, Gp);
  k_ln_enc<<<8192, 256, 0, stream>>>(xs_r, xs_i, ln_t_g, ln_t_b, encp, cl_r, cl_i);
  k_scan<<<4096, 256, 0, stream>>>(cl_r, cl_i, lam_r, lam_i, dt);
  k_dec<<<8192, 256, 0, stream>>>(xs_r, cl_r, cl_i, decp);
  k_mlp_mfma<<<8192, 256, 0, stream>>>(xs_r, xs_i, w1p, w2p, p_b1, p_b2, (float*)d_out);
}

// Round 5
// 780.672 us; speedup vs baseline: 3.0962x; 1.0434x over previous
//
#include <hip/hip_runtime.h>
#include <hip/hip_bf16.h>

#define NB 4
#define NT 16
#define ND 64
#define NHW 4096
#define NTOT (NB*NT*ND*NHW)   // 16,777,216 per plane

typedef __attribute__((ext_vector_type(8))) __bf16 bf16x8;
typedef __attribute__((ext_vector_type(4))) __bf16 bf16x4;
typedef __attribute__((ext_vector_type(4))) float f32x4;

// ---------------------------------------------------------------- complex LN (spatial)
__global__ void k_ln(const float* __restrict__ xr, const float* __restrict__ xi,
                     const float* __restrict__ g, const float* __restrict__ b,
                     float* __restrict__ outr, float* __restrict__ outi) {
  int pos = blockIdx.x * 256 + threadIdx.x;      // B*T*HW = 262144
  int bt = pos >> 12;
  int hw = pos & 4095;
  size_t base = (size_t)bt * ND * NHW + hw;
  float s = 0.f, ss = 0.f;
  for (int d = 0; d < ND; ++d) {
    float r = xr[base + (size_t)d * NHW];
    float im = xi[base + (size_t)d * NHW];
    s += r + im; ss += r * r + im * im;
  }
  float mean = s * (1.0f / 128.0f);
  float var = ss * (1.0f / 128.0f) - mean * mean;
  float rstd = rsqrtf(var + 1e-5f);
  for (int d = 0; d < ND; ++d) {
    float r = xr[base + (size_t)d * NHW];
    float im = xi[base + (size_t)d * NHW];
    outr[base + (size_t)d * NHW] = (r - mean) * rstd * g[d] + b[d];
    outi[base + (size_t)d * NHW] = (im - mean) * rstd * g[64 + d] + b[64 + d];
  }
}

// ---------------------------------------------------------------- conv weight repack
__global__ void k_wconv_repack(const float* __restrict__ w, __hip_bfloat16* __restrict__ wcp) {
  int idx = blockIdx.x * 256 + threadIdx.x;   // 147456 = 9*8*4*64*8
  int j = idx & 7;
  int lane = (idx >> 3) & 63;
  int kt = (idx >> 9) & 3;
  int nt = (idx >> 11) & 7;
  int tap = idx >> 14;
  int ic = kt * 32 + (lane >> 4) * 8 + j;
  int oc = nt * 16 + (lane & 15);
  wcp[idx] = __float2bfloat16(w[((size_t)(oc * 128 + ic)) * 9 + tap]);
}

// ---------------------------------------------------------------- 3x3 conv via MFMA (implicit GEMM)
__global__ __launch_bounds__(256) void k_conv_mfma(
    const float* __restrict__ xsr, const float* __restrict__ xsi,
    const __hip_bfloat16* __restrict__ wcp, const float* __restrict__ bias,
    __hip_bfloat16* __restrict__ cr, __hip_bfloat16* __restrict__ ci) {
  __shared__ __align__(16) __bf16 lin[3 * 66 * 128];   // 50688 B
  int blk = blockIdx.x;            // bt*64 + y
  int y = blk & 63;
  int bt = blk >> 6;
  int tid = threadIdx.x;
  int lane = tid & 63, wave = tid >> 6;
  int lc = lane & 15, quad = lane >> 4;

  for (int i = tid; i < 48 * 66; i += 256) {
    int p = i / 66;                 // p = ky*16 + icg
    int pos = i - p * 66;
    int ky = p >> 4, icg = p & 15;
    int gy = y + ky - 1, gx = pos - 1;
    float vals[8];
#pragma unroll
    for (int k = 0; k < 8; ++k) vals[k] = 0.f;
    if (gy >= 0 && gy < 64 && gx >= 0 && gx < 64) {
      const float* src = (icg < 8) ? xsr : xsi;
      size_t pbase = ((size_t)(bt * 64 + (icg & 7) * 8)) * NHW + gy * 64 + gx;
#pragma unroll
      for (int k = 0; k < 8; ++k) vals[k] = src[pbase + (size_t)k * NHW];
    }
    bf16x8 v;
#pragma unroll
    for (int k = 0; k < 8; ++k) v[k] = (__bf16)vals[k];
    int elem = ((ky * 66 + pos) * 128 + icg * 8) ^ ((pos & 7) << 3);
    *(bf16x8*)(lin + elem) = v;
  }
  __syncthreads();

  int mt0 = (wave >> 1) * 2;       // 0 or 2
  int ocb = (wave & 1) * 4;        // n-tile base: 0 or 4
  f32x4 acc[2][4];
#pragma unroll
  for (int m = 0; m < 2; ++m)
#pragma unroll
    for (int n = 0; n < 4; ++n) acc[m][n] = (f32x4){0.f, 0.f, 0.f, 0.f};

  for (int ky = 0; ky < 3; ++ky) {
#pragma unroll
    for (int kt = 0; kt < 4; ++kt) {
      bf16x8 a[3][2];
#pragma unroll
      for (int kx = 0; kx < 3; ++kx)
#pragma unroll
        for (int m = 0; m < 2; ++m) {
          int pos = (mt0 + m) * 16 + lc + kx;
          int elem = ((ky * 66 + pos) * 128 + kt * 32 + quad * 8) ^ ((pos & 7) << 3);
          a[kx][m] = *(const bf16x8*)(lin + elem);
        }
#pragma unroll
      for (int kx = 0; kx < 3; ++kx) {
        const __hip_bfloat16* wp =
            wcp + ((((size_t)(ky * 3 + kx) * 8 + ocb) * 4 + kt) * 64 + lane) * 8;
#pragma unroll
        for (int n = 0; n < 4; ++n) {
          bf16x8 b = *(const bf16x8*)(const void*)(wp + (size_t)n * (4 * 64 * 8));
#pragma unroll
          for (int m = 0; m < 2; ++m)
            acc[m][n] = __builtin_amdgcn_mfma_f32_16x16x32_bf16(a[kx][m], b, acc[m][n], 0, 0, 0);
        }
      }
    }
  }
  __syncthreads();

  __bf16* lout = lin;
#pragma unroll
  for (int n = 0; n < 4; ++n) {
    int oc = (ocb + n) * 16 + lc;
    float bb = bias[oc];
#pragma unroll
    for (int m = 0; m < 2; ++m)
#pragma unroll
      for (int r = 0; r < 4; ++r)
        lout[oc * 66 + (mt0 + m) * 16 + quad * 4 + r] = (__bf16)(acc[m][n][r] + bb);
  }
  __syncthreads();

  {
    int colh = (lane & 31) * 2;
    int ocl = lane >> 5;
#pragma unroll
    for (int it = 0; it < 16; ++it) {
      int oc = it * 8 + wave * 2 + ocl;
      __hip_bfloat16* dst = (oc < 64) ? cr : ci;
      size_t ob = ((size_t)(bt * 64 + (oc & 63))) * NHW + y * 64 + colh;
      *(unsigned int*)((void*)(dst + ob)) =
          *(const unsigned int*)((const void*)(lout + oc * 66 + colh));
    }
  }
}

// ---------------------------------------------------------------- DFT-by-MFMA helpers
__device__ __forceinline__ void gemm64x128(const __bf16* __restrict__ src,
                                           const __hip_bfloat16* __restrict__ bp,
                                           int lane, int lc, int quad, int w,
                                           f32x4 (&acc)[4][2]) {
#pragma unroll
  for (int m = 0; m < 4; ++m)
#pragma unroll
    for (int n = 0; n < 2; ++n) acc[m][n] = (f32x4){0.f, 0.f, 0.f, 0.f};
#pragma unroll
  for (int kt = 0; kt < 4; ++kt) {
    bf16x8 a[4];
#pragma unroll
    for (int m = 0; m < 4; ++m)
      a[m] = *(const bf16x8*)&src[(m * 16 + lc) * 136 + kt * 32 + quad * 8];
#pragma unroll
    for (int n = 0; n < 2; ++n) {
      int ntg = w + n * 4;
      bf16x8 b = *(const bf16x8*)(const void*)(bp + (((size_t)ntg * 4 + kt) * 64 + lane) * 8);
#pragma unroll
      for (int m = 0; m < 4; ++m)
        acc[m][n] = __builtin_amdgcn_mfma_f32_16x16x32_bf16(a[m], b, acc[m][n], 0, 0, 0);
    }
  }
}
__device__ __forceinline__ void store_T(__bf16* __restrict__ dst,
                                        int lc, int quad, int w, f32x4 (&acc)[4][2]) {
#pragma unroll
  for (int m = 0; m < 4; ++m)
#pragma unroll
    for (int n = 0; n < 2; ++n) {
      bf16x4 v;
#pragma unroll
      for (int r = 0; r < 4; ++r) v[r] = (__bf16)acc[m][n][r];
      *(bf16x4*)&dst[(w * 16 + lc) * 136 + n * 64 + m * 16 + quad * 4] = v;
    }
}

// ---------------------------------------------------------------- fused 2D DFT * W * IDFT + combine
__global__ __launch_bounds__(256) void k_fft_mfma(
    float* xsr, float* xsi,
    const __hip_bfloat16* __restrict__ cr, const __hip_bfloat16* __restrict__ ci,
    const float* __restrict__ swr, const float* __restrict__ swi,
    const float* __restrict__ x0r, const float* __restrict__ x0i,
    const float* __restrict__ gate,
    const __hip_bfloat16* __restrict__ Fp, const __hip_bfloat16* __restrict__ Gp) {
  __shared__ __align__(16) __bf16 lA[64 * 136];   // 17408 B
  __shared__ __align__(16) __bf16 lB[64 * 136];
  int slice = blockIdx.x;                         // bt*64 + d
  int d = slice & 63;
  size_t base = (size_t)slice * NHW;
  int tid = threadIdx.x, lane = tid & 63, w = tid >> 6;
  int lc = lane & 15, quad = lane >> 4;
  float g = gate[0];

  {
    int y = tid >> 2, xo = (tid & 3) * 4;
#pragma unroll
    for (int k = 0; k < 4; ++k) {
      int x = xo + k * 16;
      float4 vr = *(const float4*)(xsr + base + y * 64 + x);
      float4 vi = *(const float4*)(xsi + base + y * 64 + x);
      bf16x4 br_, bi_;
#pragma unroll
      for (int r = 0; r < 4; ++r) { br_[r] = (__bf16)(&vr.x)[r]; bi_[r] = (__bf16)(&vi.x)[r]; }
      *(bf16x4*)&lA[y * 136 + x] = br_;
      *(bf16x4*)&lA[y * 136 + 64 + x] = bi_;
    }
  }
  __syncthreads();
  f32x4 acc[4][2];
  gemm64x128(lA, Fp, lane, lc, quad, w, acc);
  store_T(lB, lc, quad, w, acc);
  __syncthreads();
  gemm64x128(lB, Fp, lane, lc, quad, w, acc);
  {
    int ky = w * 16 + lc;
    const float* wrp = swr + (size_t)d * 4096 + ky * 64;
    const float* wip = swi + (size_t)d * 4096 + ky * 64;
#pragma unroll
    for (int m = 0; m < 4; ++m) {
      int kx0 = m * 16 + quad * 4;
      float4 wr4 = *(const float4*)(wrp + kx0);
      float4 wi4 = *(const float4*)(wip + kx0);
      bf16x4 zr4, zi4;
#pragma unroll
      for (int r = 0; r < 4; ++r) {
        float yr = acc[m][0][r], yi = acc[m][1][r];
        float wr = (&wr4.x)[r], wi = (&wi4.x)[r];
        zr4[r] = (__bf16)(yr * wr - yi * wi);
        zi4[r] = (__bf16)(yr * wi + yi * wr);
      }
      *(bf16x4*)&lA[ky * 136 + kx0] = zr4;
      *(bf16x4*)&lA[ky * 136 + 64 + kx0] = zi4;
    }
  }
  __syncthreads();
  gemm64x128(lA, Gp, lane, lc, quad, w, acc);
  store_T(lB, lc, quad, w, acc);
  __syncthreads();
  gemm64x128(lB, Gp, lane, lc, quad, w, acc);
  {
    int y = w * 16 + lc;
#pragma unroll
    for (int m = 0; m < 4; ++m) {
      int x = m * 16 + quad * 4;
      size_t off = base + y * 64 + x;
      float4 v0r = *(const float4*)(x0r + off);
      float4 v0i = *(const float4*)(x0i + off);
      bf16x4 c4r = *(const bf16x4*)((const __bf16*)cr + off);
      bf16x4 c4i = *(const bf16x4*)((const __bf16*)ci + off);
      float4 outr, outi;
#pragma unroll
      for (int r = 0; r < 4; ++r) {
        (&outr.x)[r] = g * (float)c4r[r] + (1.f - g) * acc[m][0][r] + (&v0r.x)[r];
        (&outi.x)[r] = g * (float)c4i[r] + (1.f - g) * acc[m][1][r] + (&v0i.x)[r];
      }
      *(float4*)(xsr + off) = outr;
      *(float4*)(xsi + off) = outi;
    }
  }
}

// ---------------------------------------------------------------- all weight repacks (bf16, MFMA B-fragment order)
__global__ void k_repack_all(const float* __restrict__ w1, const float* __restrict__ w2,
                             const float* __restrict__ er, const float* __restrict__ ei,
                             const float* __restrict__ dmr, const float* __restrict__ dmi,
                             __hip_bfloat16* __restrict__ w1p, __hip_bfloat16* __restrict__ w2p,
                             __hip_bfloat16* __restrict__ encp, __hip_bfloat16* __restrict__ decp,
                             __hip_bfloat16* __restrict__ fp, __hip_bfloat16* __restrict__ gp) {
  int idx = blockIdx.x * 256 + threadIdx.x;   // 188416
  if (idx < 65536) {
    int j = idx & 7, lane = (idx >> 3) & 63, kt = (idx >> 9) & 3, nt = idx >> 11;
    int k = kt * 32 + (lane >> 4) * 8 + j;
    int n = nt * 16 + (lane & 15);
    w1p[idx] = __float2bfloat16(w1[k * 512 + n]);
  } else if (idx < 131072) {
    int i2 = idx - 65536;
    int j = i2 & 7, lane = (i2 >> 3) & 63, kt = (i2 >> 9) & 15, nt = i2 >> 13;
    int k = kt * 32 + (lane >> 4) * 8 + j;
    int n = nt * 16 + (lane & 15);
    w2p[i2] = __float2bfloat16(w2[k * 128 + n]);
  } else if (idx < 147456) {
    int i2 = idx - 131072;                    // enc: nt<8, kt<4
    int j = i2 & 7, lane = (i2 >> 3) & 63, kt = (i2 >> 9) & 3, nt = i2 >> 11;
    int k = kt * 32 + (lane >> 4) * 8 + j;
    int n = nt * 16 + (lane & 15);
    float v;
    if (k < 64) v = (n < 64) ? er[k * 64 + n] : ei[k * 64 + (n - 64)];
    else        v = (n < 64) ? -ei[(k - 64) * 64 + n] : er[(k - 64) * 64 + (n - 64)];
    encp[i2] = __float2bfloat16(v);
  } else if (idx < 155648) {
    int i2 = idx - 147456;                    // dec: nt<4, kt<4
    int j = i2 & 7, lane = (i2 >> 3) & 63, kt = (i2 >> 9) & 3, nt = i2 >> 11;
    int k = kt * 32 + (lane >> 4) * 8 + j;
    int n = nt * 16 + (lane & 15);
    float v = (k < 64) ? dmr[k * 64 + n] : -dmi[(k - 64) * 64 + n];
    decp[i2] = __float2bfloat16(v);
  } else if (idx < 172032) {
    int i2 = idx - 155648;                    // Fp
    int j = i2 & 7, lane = (i2 >> 3) & 63, kt = (i2 >> 9) & 3, nt = i2 >> 11;
    int k = kt * 32 + (lane >> 4) * 8 + j;
    int n = nt * 16 + (lane & 15);
    int p = ((k & 63) * (n & 63)) & 63;
    float sv, cv;
    __sincosf((float)p * 0.09817477042f, &sv, &cv);   // 2*pi/64
    float v = ((k < 64) == (n < 64)) ? cv : ((n >= 64) ? -sv : sv);
    fp[i2] = __float2bfloat16(v);
  } else {
    int i2 = idx - 172032;                    // Gp
    int j = i2 & 7, lane = (i2 >> 3) & 63, kt = (i2 >> 9) & 3, nt = i2 >> 11;
    int k = kt * 32 + (lane >> 4) * 8 + j;
    int n = nt * 16 + (lane & 15);
    int p = ((k & 63) * (n & 63)) & 63;
    float sv, cv;
    __sincosf((float)p * 0.09817477042f, &sv, &cv);
    float v = (((k < 64) == (n < 64)) ? cv : ((n >= 64) ? sv : -sv)) * 0.015625f;
    gp[i2] = __float2bfloat16(v);
  }
}

// ---------------------------------------------------------------- temporal LN + encode GEMM
__global__ __launch_bounds__(256) void k_ln_enc(
    const float* __restrict__ xsr, const float* __restrict__ xsi,
    const float* __restrict__ lng, const float* __restrict__ lnb,
    const __hip_bfloat16* __restrict__ encp,
    __hip_bfloat16* __restrict__ xer, __hip_bfloat16* __restrict__ xei) {
  __shared__ __bf16 la[32 * 136];            // 8704 B; reused as bf16 out [128][34]
  __shared__ float red_s[8][33], red_ss[8][33];
  int blk = blockIdx.x;                      // bt*128 + hwtile
  int bt = blk >> 7;
  int hw0 = (blk & 127) << 5;
  int tid = threadIdx.x;
  int lane = tid & 63, wave = tid >> 6;
  int lc = lane & 15, quad = lane >> 4;
  int tok = tid & 31, cg = tid >> 5;
  float v[16];
  float s = 0.f, ss = 0.f;
#pragma unroll
  for (int it = 0; it < 16; ++it) {
    int c = it * 8 + cg;
    const float* src = (c < 64) ? (xsr + ((size_t)(bt * 64 + c)) * NHW)
                                : (xsi + ((size_t)(bt * 64 + c - 64)) * NHW);
    v[it] = src[hw0 + tok];
    s += v[it]; ss += v[it] * v[it];
  }
  red_s[cg][tok] = s; red_ss[cg][tok] = ss;
  __syncthreads();
  float S = 0.f, SS = 0.f;
#pragma unroll
  for (int k = 0; k < 8; ++k) { S += red_s[k][tok]; SS += red_ss[k][tok]; }
  float mean = S * (1.0f / 128.0f);
  float rstd = rsqrtf(SS * (1.0f / 128.0f) - mean * mean + 1e-5f);
#pragma unroll
  for (int it = 0; it < 16; ++it) {
    int c = it * 8 + cg;
    la[tok * 136 + c] = (__bf16)((v[it] - mean) * rstd * lng[c] + lnb[c]);
  }
  __syncthreads();
  f32x4 acc[2][2];
#pragma unroll
  for (int m = 0; m < 2; ++m)
#pragma unroll
    for (int n = 0; n < 2; ++n) acc[m][n] = (f32x4){0.f, 0.f, 0.f, 0.f};
#pragma unroll
  for (int kt = 0; kt < 4; ++kt) {
    bf16x8 a0 = *(const bf16x8*)&la[lc * 136 + kt * 32 + quad * 8];
    bf16x8 a1 = *(const bf16x8*)&la[(lc + 16) * 136 + kt * 32 + quad * 8];
#pragma unroll
    for (int n = 0; n < 2; ++n) {
      int ntg = wave * 2 + n;
      bf16x8 b = *(const bf16x8*)(const void*)(encp + (((size_t)ntg * 4 + kt) * 64 + lane) * 8);
      acc[0][n] = __builtin_amdgcn_mfma_f32_16x16x32_bf16(a0, b, acc[0][n], 0, 0, 0);
      acc[1][n] = __builtin_amdgcn_mfma_f32_16x16x32_bf16(a1, b, acc[1][n], 0, 0, 0);
    }
  }
  __syncthreads();
  __bf16* lo = la;
#pragma unroll
  for (int n = 0; n < 2; ++n) {
    int c = (wave * 2 + n) * 16 + lc;
#pragma unroll
    for (int m = 0; m < 2; ++m)
#pragma unroll
      for (int r = 0; r < 4; ++r)
        lo[c * 34 + m * 16 + quad * 4 + r] = (__bf16)acc[m][n][r];
  }
  __syncthreads();
  {
    int tokh = tid & 15, cc = tid >> 4;
#pragma unroll
    for (int it = 0; it < 8; ++it) {
      int c = it * 16 + cc;
      __hip_bfloat16* dst = (c < 64) ? xer : xei;
      size_t ob = ((size_t)(bt * 64 + (c & 63))) * NHW + hw0 + tokh * 2;
      *(unsigned int*)((void*)(dst + ob)) =
          *(const unsigned int*)((const void*)(lo + c * 34 + tokh * 2));
    }
  }
}

// ---------------------------------------------------------------- diagonal ZOH scan (in-place over x_eigen)
__global__ __launch_bounds__(256) void k_scan(
    __hip_bfloat16* xer, __hip_bfloat16* xei,
    const float* __restrict__ lam_r, const float* __restrict__ lam_i,
    const float* __restrict__ dtv) {
  int idx = blockIdx.x * 256 + threadIdx.x;   // B*64*NHW = 1048576
  int hw = idx & 4095;
  int e = (idx >> 12) & 63;
  int b = idx >> 18;
  float lrv = lam_r[e], liv = lam_i[e];
  float dtb = dtv[b];
  float mg = __expf(lrv * dtb);
  float sn, cs;
  __sincosf(liv * dtb, &sn, &cs);
  float der = mg * cs, dei = mg * sn;
  float nr = der - 1.0f, ni = dei;
  float dn = 1.0f / (lrv * lrv + liv * liv);
  float forr = (nr * lrv + ni * liv) * dn;
  float fori = (ni * lrv - nr * liv) * dn;
  float hr = 0.f, hi = 0.f;
  size_t base = ((size_t)(b * NT * ND + e)) * NHW + hw;
  for (int t = 0; t < NT; ++t) {
    size_t off = base + (size_t)t * ND * NHW;
    float ur = __bfloat162float(xer[off]);
    float ui = __bfloat162float(xei[off]);
    float h0r = hr, h0i = hi;
    hr = h0r * der - h0i * dei + ur * forr - ui * fori;
    hi = h0r * dei + h0i * der + ur * fori + ui * forr;
    xer[off] = __float2bfloat16(hr);
    xei[off] = __float2bfloat16(hi);
  }
}

// ---------------------------------------------------------------- decode GEMM + residual add into xs_r
__global__ __launch_bounds__(256) void k_dec(
    float* __restrict__ xsr,
    const __hip_bfloat16* __restrict__ her, const __hip_bfloat16* __restrict__ hei,
    const __hip_bfloat16* __restrict__ decp) {
  __shared__ __bf16 lh2[32 * 136];           // 8704 B; reused as fp32 lo[64][33] (8448 B)
  int blk = blockIdx.x;                      // bt*128 + hwtile
  int bt = blk >> 7;
  int hw0 = (blk & 127) << 5;
  int tid = threadIdx.x;
  int lane = tid & 63, wave = tid >> 6;
  int lc = lane & 15, quad = lane >> 4;
  {
    int tok = tid & 31, cg = tid >> 5;
#pragma unroll
    for (int it = 0; it < 16; ++it) {
      int c = it * 8 + cg;
      const __hip_bfloat16* src = (c < 64) ? (her + ((size_t)(bt * 64 + c)) * NHW)
                                           : (hei + ((size_t)(bt * 64 + c - 64)) * NHW);
      lh2[tok * 136 + c] = ((const __bf16*)src)[hw0 + tok];
    }
  }
  __syncthreads();
  f32x4 acc[2];
  acc[0] = (f32x4){0.f, 0.f, 0.f, 0.f};
  acc[1] = (f32x4){0.f, 0.f, 0.f, 0.f};
#pragma unroll
  for (int kt = 0; kt < 4; ++kt) {
    bf16x8 a0 = *(const bf16x8*)&lh2[lc * 136 + kt * 32 + quad * 8];
    bf16x8 a1 = *(const bf16x8*)&lh2[(lc + 16) * 136 + kt * 32 + quad * 8];
    bf16x8 b = *(const bf16x8*)(const void*)(decp + (((size_t)wave * 4 + kt) * 64 + lane) * 8);
    acc[0] = __builtin_amdgcn_mfma_f32_16x16x32_bf16(a0, b, acc[0], 0, 0, 0);
    acc[1] = __builtin_amdgcn_mfma_f32_16x16x32_bf16(a1, b, acc[1], 0, 0, 0);
  }
  __syncthreads();
  float* lo = (float*)lh2;
  {
    int c = wave * 16 + lc;
#pragma unroll
    for (int m = 0; m < 2; ++m)
#pragma unroll
      for (int r = 0; r < 4; ++r)
        lo[c * 33 + m * 16 + quad * 4 + r] = acc[m][r];
  }
  __syncthreads();
  {
    int tok = tid & 31, cg = tid >> 5;
#pragma unroll
    for (int it = 0; it < 8; ++it) {
      int c = it * 8 + cg;
      size_t off = ((size_t)(bt * 64 + c)) * NHW + hw0 + tok;
      xsr[off] += lo[c * 33 + tok];
    }
  }
}

// ---------------------------------------------------------------- channel MLP via MFMA
// 64 tokens/block, 512 threads (8 waves), f-dim split into two 256-halves.
// lf[64][136] bf16 (17408 B) + lh[64][264] bf16 (33792 B, reused as fp32 lo[128][66]) = 51200 B
__global__ __launch_bounds__(512, 6) void k_mlp_mfma(
    const float* __restrict__ xsr, const float* __restrict__ xsi,
    const __hip_bfloat16* __restrict__ w1p, const __hip_bfloat16* __restrict__ w2p,
    const float* __restrict__ b1, const float* __restrict__ b2,
    float* __restrict__ out) {
  __shared__ __align__(16) __bf16 lf[64 * 136];
  __shared__ __align__(16) __bf16 lh[64 * 264];
  float* lo = (float*)lh;                  // [128][66] fp32 = 33792 B (exact)
  int blk = blockIdx.x;                    // 4096 = bt*64 + hwtile
  int bt = blk >> 6;
  int hw0 = (blk & 63) << 6;
  int tid = threadIdx.x;
  int lane = tid & 63, wave = tid >> 6;
  int lc = lane & 15, quad = lane >> 4;
  // ---- stage f (fp32 global float4 -> bf16 LDS) ----
  {
    int tok4 = (tid & 15) * 4, cgrp = tid >> 4;   // cgrp 0..31
#pragma unroll
    for (int it = 0; it < 4; ++it) {
      int c = it * 32 + cgrp;
      const float* src = (c < 64) ? (xsr + ((size_t)(bt * 64 + c)) * NHW)
                                  : (xsi + ((size_t)(bt * 64 + c - 64)) * NHW);
      float4 v = *(const float4*)(src + hw0 + tok4);
#pragma unroll
      for (int r = 0; r < 4; ++r) lf[(tok4 + r) * 136 + c] = (__bf16)(&v.x)[r];
    }
  }
  __syncthreads();
  f32x4 acc2[4];
#pragma unroll
  for (int m = 0; m < 4; ++m) acc2[m] = (f32x4){0.f, 0.f, 0.f, 0.f};
#pragma unroll
  for (int fb = 0; fb < 2; ++fb) {
    // ---- GEMM1 half: h1[64][256], wave owns 32 f-cols (n-outer to cap VGPR) ----
#pragma unroll
    for (int n = 0; n < 2; ++n) {
      f32x4 acc1[4];
#pragma unroll
      for (int m = 0; m < 4; ++m) acc1[m] = (f32x4){0.f, 0.f, 0.f, 0.f};
      int ntg = fb * 16 + wave * 2 + n;
#pragma unroll
      for (int kt = 0; kt < 4; ++kt) {
        bf16x8 b = *(const bf16x8*)(const void*)(w1p + (((size_t)ntg * 4 + kt) * 64 + lane) * 8);
#pragma unroll
        for (int m = 0; m < 4; ++m) {
          bf16x8 a = *(const bf16x8*)&lf[(m * 16 + lc) * 136 + kt * 32 + quad * 8];
          acc1[m] = __builtin_amdgcn_mfma_f32_16x16x32_bf16(a, b, acc1[m], 0, 0, 0);
        }
      }
      // ---- gelu (sigmoid form, exp2 + rcp) -> lh ----
      int f_loc = (wave * 2 + n) * 16 + lc;
      float bb = b1[fb * 256 + f_loc];
#pragma unroll
      for (int m = 0; m < 4; ++m)
#pragma unroll
        for (int r = 0; r < 4; ++r) {
          float x = acc1[m][r] + bb;
          float u = __builtin_fmaf(-0.1029453f, x * x, -2.3022077f);  // -2*log2e*(a + b x^2)
          float e = exp2f(x * u);
          float gv = x * __builtin_amdgcn_rcpf(1.0f + e);
          lh[(m * 16 + quad * 4 + r) * 264 + f_loc] = (__bf16)gv;
        }
    }
    __syncthreads();   // gelu stores visible
    // ---- GEMM2 half-accumulate: out[64][128], wave owns 16 c-cols ----
#pragma unroll
    for (int kt = 0; kt < 8; ++kt) {
      bf16x8 b = *(const bf16x8*)(const void*)(w2p + (((size_t)(wave * 16 + fb * 8 + kt) * 64 + lane)) * 8);
#pragma unroll
      for (int m = 0; m < 4; ++m) {
        bf16x8 a = *(const bf16x8*)&lh[(m * 16 + lc) * 264 + kt * 32 + quad * 8];
        acc2[m] = __builtin_amdgcn_mfma_f32_16x16x32_bf16(a, b, acc2[m], 0, 0, 0);
      }
    }
    __syncthreads();   // lh reads done (next half's stores / lo reuse)
  }
  // ---- epilogue: acc2 + b2 -> lo[c][tok] ----
  {
    int c = wave * 16 + lc;
    float bb = b2[c];
#pragma unroll
    for (int m = 0; m < 4; ++m)
#pragma unroll
      for (int r = 0; r < 4; ++r)
        lo[c * 66 + m * 16 + quad * 4 + r] = acc2[m][r] + bb;
  }
  __syncthreads();
  // ---- final: out = lo + f_resid (fp32), float4 coalesced ----
  {
    int tok4 = (tid & 15) * 4, cgrp = tid >> 4;
#pragma unroll
    for (int it = 0; it < 4; ++it) {
      int c = it * 32 + cgrp;
      const float* src = (c < 64) ? (xsr + ((size_t)(bt * 64 + c)) * NHW)
                                  : (xsi + ((size_t)(bt * 64 + c - 64)) * NHW);
      float4 rv = *(const float4*)(src + hw0 + tok4);
      float4 o;
#pragma unroll
      for (int r = 0; r < 4; ++r) (&o.x)[r] = lo[c * 66 + tok4 + r] + (&rv.x)[r];
      *(float4*)(out + ((size_t)(bt * 128 + c)) * NHW + hw0 + tok4) = o;
    }
  }
}

// ---------------------------------------------------------------- launch
extern "C" void kernel_launch(void* const* d_in, const int* in_sizes, int n_in,
                              void* d_out, int out_size, void* d_ws, size_t ws_size,
                              hipStream_t stream) {
  const float* x_r    = (const float*)d_in[0];
  const float* x_i    = (const float*)d_in[1];
  const float* dt     = (const float*)d_in[2];
  const float* ln_s_g = (const float*)d_in[3];
  const float* ln_s_b = (const float*)d_in[4];
  const float* conv_w = (const float*)d_in[5];
  const float* conv_b = (const float*)d_in[6];
  const float* spec_wr= (const float*)d_in[7];
  const float* spec_wi= (const float*)d_in[8];
  const float* gate   = (const float*)d_in[9];
  const float* ln_t_g = (const float*)d_in[10];
  const float* ln_t_b = (const float*)d_in[11];
  const float* lam_r  = (const float*)d_in[12];
  const float* lam_i  = (const float*)d_in[13];
  const float* enc_r  = (const float*)d_in[14];
  const float* enc_i  = (const float*)d_in[15];
  const float* dec_r  = (const float*)d_in[16];
  const float* dec_i  = (const float*)d_in[17];
  const float* p_w1   = (const float*)d_in[18];
  const float* p_b1   = (const float*)d_in[19];
  const float* p_w2   = (const float*)d_in[20];
  const float* p_b2   = (const float*)d_in[21];

  float* ws   = (float*)d_ws;
  float* xs_r = ws;                       // N fp32
  float* xs_i = ws + (size_t)NTOT;        // N fp32
  __hip_bfloat16* sbpack = (__hip_bfloat16*)(ws + (size_t)2 * NTOT);
  __hip_bfloat16* w1p  = sbpack;              // 65536
  __hip_bfloat16* w2p  = sbpack + 65536;      // 65536
  __hip_bfloat16* encp = sbpack + 131072;     // 16384
  __hip_bfloat16* decp = sbpack + 147456;     // 8192
  __hip_bfloat16* Fp   = sbpack + 155648;     // 16384
  __hip_bfloat16* Gp   = sbpack + 172032;     // 16384
  __hip_bfloat16* cl_r = (__hip_bfloat16*)(ws + (size_t)2 * NTOT + (size_t)2 * ND * NHW);  // N bf16
  __hip_bfloat16* cl_i = cl_r + (size_t)NTOT;                                              // N bf16
  __hip_bfloat16* wcp = (__hip_bfloat16*)d_out;   // 147456 bf16

  k_repack_all<<<736, 256, 0, stream>>>(p_w1, p_w2, enc_r, enc_i, dec_r, dec_i,
                                        w1p, w2p, encp, decp, Fp, Gp);
  k_wconv_repack<<<576, 256, 0, stream>>>(conv_w, wcp);
  k_ln<<<1024, 256, 0, stream>>>(x_r, x_i, ln_s_g, ln_s_b, xs_r, xs_i);
  k_conv_mfma<<<4096, 256, 0, stream>>>(xs_r, xs_i, wcp, conv_b, cl_r, cl_i);
  k_fft_mfma<<<4096, 256, 0, stream>>>(xs_r, xs_i, cl_r, cl_i, spec_wr, spec_wi,
                                       x_r, x_i, gate, Fp, Gp);
  k_ln_enc<<<8192, 256, 0, stream>>>(xs_r, xs_i, ln_t_g, ln_t_b, encp, cl_r, cl_i);
  k_scan<<<4096, 256, 0, stream>>>(cl_r, cl_i, lam_r, lam_i, dt);
  k_dec<<<8192, 256, 0, stream>>>(xs_r, cl_r, cl_i, decp);
  k_mlp_mfma<<<4096, 512, 0, stream>>>(xs_r, xs_i, w1p, w2p, p_b1, p_b2, (float*)d_out);
}